// Round 1
// baseline (983.979 us; speedup 1.0000x reference)
//
#include <hip/hip_runtime.h>
#include <cstdint>

// Problem constants (match reference)
constexpr int B_ = 8;
constexpr int P_ = 16384;
constexpr int K_ = 100;
constexpr int M_ = P_ * 4;          // 65536 candidates per image (classes 1..4)
constexpr float NEGF = -1e30f;
constexpr float SCORE_T = 0.05f;
constexpr float CLIPV = 4.135166556742356f;  // log(1000/16) as f32

// ---------------------------------------------------------------------------
// Kernel 1: per-proposal softmax + box decode + clip; store candidate boxes,
// masked scores; per-image max box coordinate (for the batched_nms offset).
// One thread per proposal n in [0, B*P).
// ---------------------------------------------------------------------------
__global__ __launch_bounds__(256) void prep_kernel(
    const float* __restrict__ logits,     // [N,5]
    const float* __restrict__ boxreg,     // [N,20]
    const float* __restrict__ props,      // [N,4]
    const int*  __restrict__ image_hw,    // [2] = {H, W}
    float* __restrict__ wboxes,           // [B*M,4]
    float* __restrict__ wscores,          // [B*M]
    int*   __restrict__ wmax)             // [B] float bits of per-image max coord
{
  const int n = blockIdx.x * 256 + threadIdx.x;   // exact: 512*256 = 131072 = B*P

  // softmax over 5 logits (same op order as jax.nn.softmax)
  float l[5];
#pragma unroll
  for (int i = 0; i < 5; ++i) l[i] = logits[n * 5 + i];
  float mx = l[0];
#pragma unroll
  for (int i = 1; i < 5; ++i) mx = fmaxf(mx, l[i]);
  float e[5];
  float ssum = 0.f;
#pragma unroll
  for (int i = 0; i < 5; ++i) { e[i] = expf(l[i] - mx); ssum += e[i]; }

  const float4 pr = reinterpret_cast<const float4*>(props)[n];
  const float w  = pr.z - pr.x;
  const float h  = pr.w - pr.y;
  const float cx = pr.x + 0.5f * w;
  const float cy = pr.y + 0.5f * h;
  const float Hf = (float)image_hw[0];
  const float Wf = (float)image_hw[1];

  float bmax = 0.f;
  float sc[4];
#pragma unroll
  for (int c = 1; c < 5; ++c) {
    const float4 rel = reinterpret_cast<const float4*>(boxreg)[n * 5 + c];
    const float dx = rel.x / 10.0f;
    const float dy = rel.y / 10.0f;
    const float dw = fminf(rel.z / 5.0f, CLIPV);
    const float dh = fminf(rel.w / 5.0f, CLIPV);
    const float pcx = dx * w + cx;
    const float pcy = dy * h + cy;
    const float pw = expf(dw) * w;
    const float ph = expf(dh) * h;
    float x1 = pcx - 0.5f * pw, y1 = pcy - 0.5f * ph;
    float x2 = pcx + 0.5f * pw, y2 = pcy + 0.5f * ph;
    x1 = fminf(fmaxf(x1, 0.f), Wf);
    x2 = fminf(fmaxf(x2, 0.f), Wf);
    y1 = fminf(fmaxf(y1, 0.f), Hf);
    y2 = fminf(fmaxf(y2, 0.f), Hf);
    reinterpret_cast<float4*>(wboxes)[n * 4 + (c - 1)] = make_float4(x1, y1, x2, y2);
    bmax = fmaxf(bmax, fmaxf(fmaxf(x1, x2), fmaxf(y1, y2)));
    const float scv = e[c] / ssum;
    sc[c - 1] = (scv > SCORE_T) ? scv : NEGF;
  }
  reinterpret_cast<float4*>(wscores)[n] = make_float4(sc[0], sc[1], sc[2], sc[3]);

  // block max-reduce -> one atomic per block (all n in a block share one image)
  __shared__ float red[256];
  red[threadIdx.x] = bmax;
  __syncthreads();
#pragma unroll
  for (int off = 128; off > 0; off >>= 1) {
    if (threadIdx.x < off) red[threadIdx.x] = fmaxf(red[threadIdx.x], red[threadIdx.x + off]);
    __syncthreads();
  }
  if (threadIdx.x == 0) {
    const int b = n >> 14;  // n / P
    atomicMax(&wmax[b], __float_as_int(red[0]));  // coords >= 0: int bits order ok
  }
}

// rescan a thread's 64 scores, honoring the active-bit mask.
// strict '>' on ascending index == jnp.argmax tie-break (lowest index).
__device__ inline void scan_max(const float4* __restrict__ s4,
                                unsigned long long mask, int t,
                                float& lmax, int& lidx)
{
  lmax = NEGF;
  lidx = t * 64;
#pragma unroll
  for (int q = 0; q < 16; ++q) {
    const float4 v = s4[q];
    const int k0 = q * 4;
    float vv;
    vv = ((mask >> (k0 + 0)) & 1ull) ? v.x : NEGF; if (vv > lmax) { lmax = vv; lidx = t * 64 + k0 + 0; }
    vv = ((mask >> (k0 + 1)) & 1ull) ? v.y : NEGF; if (vv > lmax) { lmax = vv; lidx = t * 64 + k0 + 1; }
    vv = ((mask >> (k0 + 2)) & 1ull) ? v.z : NEGF; if (vv > lmax) { lmax = vv; lidx = t * 64 + k0 + 2; }
    vv = ((mask >> (k0 + 3)) & 1ull) ? v.w : NEGF; if (vv > lmax) { lmax = vv; lidx = t * 64 + k0 + 3; }
  }
}

// ---------------------------------------------------------------------------
// Kernel 2: per-image greedy NMS (K=100 argmax+suppress iterations) + output
// gather. One 1024-thread block per image; each thread owns 64 candidates.
// ---------------------------------------------------------------------------
__global__ __launch_bounds__(1024) void nms_kernel(
    const float* __restrict__ boxes,     // [B*M,4] decoded+clipped
    const float* __restrict__ scores,    // [B*M] masked (NEG if <= 0.05)
    const int*  __restrict__ wmax,       // [B]
    const float* __restrict__ handside,  // [N,5]
    const float* __restrict__ dxdymag,   // [N,15]
    const float* __restrict__ contact,   // [N,25]
    float* __restrict__ out)             // 9600 floats, concatenated outputs
{
  const int b = blockIdx.x;
  const int t = threadIdx.x;
  const int base = b * M_;
  const float maxv1 = __int_as_float(wmax[b]) + 1.0f;  // (boxes.max() + 1.0)

  __shared__ float lwv[16];
  __shared__ int   lwi[16];
  __shared__ float winv_s;
  __shared__ int   wini_s;
  __shared__ int   resi[K_];
  __shared__ float resv[K_];
  __shared__ int   count_s;
  if (t == 0) count_s = 0;

  const float4* s4 = reinterpret_cast<const float4*>(scores + base) + t * 16;

  // initial activity mask (score != NEG i.e. passed the 0.05 threshold)
  unsigned long long mask = 0ull;
#pragma unroll
  for (int q = 0; q < 16; ++q) {
    const float4 v = s4[q];
    const int k0 = q * 4;
    if (v.x != NEGF) mask |= 1ull << (k0 + 0);
    if (v.y != NEGF) mask |= 1ull << (k0 + 1);
    if (v.z != NEGF) mask |= 1ull << (k0 + 2);
    if (v.w != NEGF) mask |= 1ull << (k0 + 3);
  }
  float lmax; int lidx;
  scan_max(s4, mask, t, lmax, lidx);

  for (int r = 0; r < K_; ++r) {
    // wave argmax (64 lanes), lowest-index tie-break
    float wv = lmax; int wi = lidx;
#pragma unroll
    for (int off = 32; off > 0; off >>= 1) {
      const float ov = __shfl_down(wv, off);
      const int   oi = __shfl_down(wi, off);
      if (ov > wv || (ov == wv && oi < wi)) { wv = ov; wi = oi; }
    }
    if ((t & 63) == 0) { lwv[t >> 6] = wv; lwi[t >> 6] = wi; }
    __syncthreads();
    if (t == 0) {
      float bv = lwv[0]; int bi = lwi[0];
#pragma unroll
      for (int q = 1; q < 16; ++q) {
        const float v = lwv[q]; const int i = lwi[q];
        if (v > bv || (v == bv && i < bi)) { bv = v; bi = i; }
      }
      winv_s = bv; wini_s = bi;
      if (bv > -5e29f) { resi[r] = bi; resv[r] = bv; count_s = r + 1; }
    }
    __syncthreads();
    const float bwv = winv_s;
    const int   bwi = wini_s;
    if (bwv <= -5e29f) break;   // all remaining scores are NEG -> keep=false forever

    // suppression: winner's class only (cross-class IoU is exactly 0 with the
    // batched_nms offset). Apply the offset to match reference rounding.
    const int wcls = bwi & 3;
    const float offv = (float)(wcls + 1) * maxv1;
    float4 wb = reinterpret_cast<const float4*>(boxes)[base + bwi];
    wb.x += offv; wb.y += offv; wb.z += offv; wb.w += offv;
    const float wa = (wb.z - wb.x) * (wb.w - wb.y);

    bool dirty = false;
    if ((bwi >> 6) == t) { mask &= ~(1ull << (bwi & 63)); dirty = true; }  // s.at[i].set(NEG)

    for (int k = wcls; k < 64; k += 4) {
      if (mask & (1ull << k)) {
        float4 bb = reinterpret_cast<const float4*>(boxes)[base + t * 64 + k];
        bb.x += offv; bb.y += offv; bb.z += offv; bb.w += offv;
        const float ltx = fmaxf(wb.x, bb.x);
        const float lty = fmaxf(wb.y, bb.y);
        const float rbx = fminf(wb.z, bb.z);
        const float rby = fminf(wb.w, bb.w);
        const float iw = fmaxf(rbx - ltx, 0.f);
        const float ih = fmaxf(rby - lty, 0.f);
        const float inter = iw * ih;
        const float ab = (bb.z - bb.x) * (bb.w - bb.y);
        const float iou = inter / (wa + ab - inter);   // NaN > 0.5 is false (matches)
        if (iou > 0.5f) { mask &= ~(1ull << k); dirty = true; }
      }
    }
    if (dirty) scan_max(s4, mask, t, lmax, lidx);
  }
  __syncthreads();

  // ---------------- gather outputs (threads 0..99 handle one slot each) -----
  if (t < K_) {
    const int r = t;
    const int cnt = count_s;
    float ob0 = 0.f, ob1 = 0.f, ob2 = 0.f, ob3 = 0.f;
    float osc = 0.f, olab = 0.f, oside = 0.f;
    float od0 = 0.f, od1 = 0.f, od2 = 0.f;
    float ocon = 0.f, okeep = 0.f;
    if (r < cnt) {
      const int idx = resi[r];
      const float val = resv[r];
      const int p = idx >> 2;
      const int cls = (idx & 3) + 1;
      const int n = b * P_ + p;
      const float4 bx = reinterpret_cast<const float4*>(boxes)[base + idx];
      ob0 = bx.x; ob1 = bx.y; ob2 = bx.z; ob3 = bx.w;
      osc = val;
      olab = (float)cls;
      oside = (handside[n * 5 + cls] > 0.f) ? 1.f : 0.f;   // sigmoid(x)>0.5 <=> x>0
      od0 = dxdymag[n * 15 + cls * 3 + 0];
      od1 = dxdymag[n * 15 + cls * 3 + 1];
      od2 = dxdymag[n * 15 + cls * 3 + 2];
      // contacts: first-max argmax over 5
      float bvv = contact[n * 25 + cls * 5 + 0];
      int best = 0;
#pragma unroll
      for (int i = 1; i < 5; ++i) {
        const float ci = contact[n * 25 + cls * 5 + i];
        if (ci > bvv) { bvv = ci; best = i; }
      }
      ocon = (float)best;
      okeep = 1.f;
    }
    const int gb = b * K_ + r;
    // boxes [0, 3200)
    out[gb * 4 + 0] = ob0;
    out[gb * 4 + 1] = ob1;
    out[gb * 4 + 2] = ob2;
    out[gb * 4 + 3] = ob3;
    // scores [3200, 4000)
    out[3200 + gb] = osc;
    // labels [4000, 4800)
    out[4000 + gb] = olab;
    // sides [4800, 5600)
    out[4800 + gb] = oside;
    // dxdy [5600, 8000)
    out[5600 + gb * 3 + 0] = od0;
    out[5600 + gb * 3 + 1] = od1;
    out[5600 + gb * 3 + 2] = od2;
    // contacts [8000, 8800)
    out[8000 + gb] = ocon;
    // keep [8800, 9600)
    out[8800 + gb] = okeep;
  }
}

// ---------------------------------------------------------------------------
extern "C" void kernel_launch(void* const* d_in, const int* in_sizes, int n_in,
                              void* d_out, int out_size, void* d_ws, size_t ws_size,
                              hipStream_t stream) {
  const float* class_logits = (const float*)d_in[0];
  const float* box_reg      = (const float*)d_in[1];
  const float* handside     = (const float*)d_in[2];
  const float* dxdymag      = (const float*)d_in[3];
  const float* contact      = (const float*)d_in[4];
  const float* proposals    = (const float*)d_in[5];
  const int*   image_hw     = (const int*)d_in[6];
  float* out = (float*)d_out;

  char* ws = (char*)d_ws;
  float* wboxes  = (float*)ws;                              // 8 MiB: B*M*4 f32
  float* wscores = (float*)(ws + (size_t)8 * 1024 * 1024);  // 2 MiB: B*M f32
  int*   wmax    = (int*)  (ws + (size_t)10 * 1024 * 1024); // 32 B : B ints

  hipMemsetAsync(wmax, 0, B_ * sizeof(int), stream);
  prep_kernel<<<dim3(512), dim3(256), 0, stream>>>(
      class_logits, box_reg, proposals, image_hw, wboxes, wscores, wmax);
  nms_kernel<<<dim3(B_), dim3(1024), 0, stream>>>(
      wboxes, wscores, wmax, handside, dxdymag, contact, out);
}

// Round 2
// 239.044 us; speedup vs baseline: 4.1163x; 4.1163x over previous
//
#include <hip/hip_runtime.h>
#include <cstdint>

constexpr int B_ = 8;
constexpr int P_ = 16384;
constexpr int K_ = 100;
constexpr int M_ = P_ * 4;          // 65536 candidates per image
constexpr int CH = 128;             // NMS scan chunk size
constexpr float NEGF = -1e30f;
constexpr float SCORE_T = 0.05f;
constexpr float CLIPV = 4.135166556742356f;  // log(1000/16)

// ---------------------------------------------------------------------------
// Kernel 1: softmax + decode + clip. Writes boxes [B*M,4], per-class scores
// transposed [B*4][P] (NEG-masked), and per-image max coordinate.
// ---------------------------------------------------------------------------
__global__ __launch_bounds__(256) void prep_kernel(
    const float* __restrict__ logits,     // [N,5]
    const float* __restrict__ boxreg,     // [N,20]
    const float* __restrict__ props,      // [N,4]
    const int*  __restrict__ image_hw,    // {H, W}
    float* __restrict__ wboxes,           // [B*M,4]
    float* __restrict__ wscoresT,         // [B*4*P]
    int*   __restrict__ wmax)             // [B]
{
  const int n = blockIdx.x * 256 + threadIdx.x;   // 512*256 == B*P

  float l[5];
#pragma unroll
  for (int i = 0; i < 5; ++i) l[i] = logits[n * 5 + i];
  float mx = l[0];
#pragma unroll
  for (int i = 1; i < 5; ++i) mx = fmaxf(mx, l[i]);
  float e[5]; float ssum = 0.f;
#pragma unroll
  for (int i = 0; i < 5; ++i) { e[i] = expf(l[i] - mx); ssum += e[i]; }

  const float4 pr = reinterpret_cast<const float4*>(props)[n];
  const float w  = pr.z - pr.x;
  const float h  = pr.w - pr.y;
  const float cx = pr.x + 0.5f * w;
  const float cy = pr.y + 0.5f * h;
  const float Hf = (float)image_hw[0];
  const float Wf = (float)image_hw[1];

  const int b = n >> 14;
  const int p = n & (P_ - 1);

  float bmax = 0.f;
#pragma unroll
  for (int c = 1; c < 5; ++c) {
    const float4 rel = reinterpret_cast<const float4*>(boxreg)[n * 5 + c];
    const float dx = rel.x / 10.0f;
    const float dy = rel.y / 10.0f;
    const float dw = fminf(rel.z / 5.0f, CLIPV);
    const float dh = fminf(rel.w / 5.0f, CLIPV);
    const float pcx = dx * w + cx;
    const float pcy = dy * h + cy;
    const float pw = expf(dw) * w;
    const float ph = expf(dh) * h;
    float x1 = pcx - 0.5f * pw, y1 = pcy - 0.5f * ph;
    float x2 = pcx + 0.5f * pw, y2 = pcy + 0.5f * ph;
    x1 = fminf(fmaxf(x1, 0.f), Wf);
    x2 = fminf(fmaxf(x2, 0.f), Wf);
    y1 = fminf(fmaxf(y1, 0.f), Hf);
    y2 = fminf(fmaxf(y2, 0.f), Hf);
    reinterpret_cast<float4*>(wboxes)[n * 4 + (c - 1)] = make_float4(x1, y1, x2, y2);
    bmax = fmaxf(bmax, fmaxf(fmaxf(x1, x2), fmaxf(y1, y2)));
    const float scv = e[c] / ssum;
    wscoresT[((size_t)(b * 4 + (c - 1))) * P_ + p] = (scv > SCORE_T) ? scv : NEGF;
  }

  __shared__ float red[256];
  red[threadIdx.x] = bmax;
  __syncthreads();
#pragma unroll
  for (int off = 128; off > 0; off >>= 1) {
    if (threadIdx.x < off) red[threadIdx.x] = fmaxf(red[threadIdx.x], red[threadIdx.x + off]);
    __syncthreads();
  }
  if (threadIdx.x == 0) atomicMax(&wmax[b], __float_as_int(red[0]));
}

// butterfly argmax over 64 lanes: max value, tie -> min index. all lanes converge.
__device__ inline void wave_argmax(float& v, int& p) {
#pragma unroll
  for (int off = 32; off > 0; off >>= 1) {
    const float ov = __shfl_xor(v, off);
    const int   op = __shfl_xor(p, off);
    if (ov > v || (ov == v && op < p)) { v = ov; p = op; }
  }
}

// ---------------------------------------------------------------------------
// Kernel 2: per-(image,class) sorted-order NMS. One 64-thread wave per task.
// Candidate p owned by lane L=(p>>2)&63, slot m=((p>>8)<<2)|(p&3); scores in
// LDS at sc[m*65+L] (65-pad -> conflict-free for both access patterns).
// ---------------------------------------------------------------------------
__global__ __launch_bounds__(64) void nms_class_kernel(
    const float* __restrict__ boxes,     // [B*M,4]
    const float* __restrict__ scoresT,   // [B*4*P]
    const int*  __restrict__ wmax,       // [B]
    int*   __restrict__ g_keptp,         // [32*K]
    float* __restrict__ g_kepts,         // [32*K]
    int*   __restrict__ g_kcount)        // [32]
{
  const int task = blockIdx.x;
  const int b = task >> 2, cm1 = task & 3;
  const int lane = threadIdx.x;
  const float maxv1 = __int_as_float(wmax[b]) + 1.0f;
  const float offv = (float)(cm1 + 1) * maxv1;

  __shared__ float  sc[256 * 65];
  __shared__ float  chunk_s[CH];
  __shared__ int    chunk_p[CH];
  __shared__ float4 boxlist[CH];
  __shared__ float4 keptbox[K_];   // offset coords
  __shared__ float  karea[K_];
  __shared__ int    keptpl[K_];
  __shared__ float  keptsl[K_];

  // load scores (coalesced float4) -> LDS; build per-lane head on the fly
  const float4* s4g = reinterpret_cast<const float4*>(scoresT + (size_t)task * P_);
  float hv = NEGF; int hp = lane * 4;
#pragma unroll 8
  for (int i = 0; i < 64; ++i) {
    const float4 v = s4g[i * 64 + lane];
    const int p0 = i * 256 + lane * 4;
    const int m0 = i * 4;
    sc[(m0 + 0) * 65 + lane] = v.x;
    sc[(m0 + 1) * 65 + lane] = v.y;
    sc[(m0 + 2) * 65 + lane] = v.z;
    sc[(m0 + 3) * 65 + lane] = v.w;
    if (v.x > hv) { hv = v.x; hp = p0 + 0; }
    if (v.y > hv) { hv = v.y; hp = p0 + 1; }
    if (v.z > hv) { hv = v.z; hp = p0 + 2; }
    if (v.w > hv) { hv = v.w; hp = p0 + 3; }
  }
  __syncthreads();

  int kept = 0;
  bool exhausted = false;

  while (kept < K_ && !exhausted) {
    // ---- phase 1: pop next CH candidates in (score desc, p asc) order ----
    int clen = 0;
    for (; clen < CH; ++clen) {
      float v = hv; int p = hp;
      wave_argmax(v, p);
      if (v <= -5e29f) { exhausted = true; break; }
      if (lane == 0) { chunk_s[clen] = v; chunk_p[clen] = p; }
      const int owner = (p >> 2) & 63;
      const int m = ((p >> 8) << 2) | (p & 3);
      if (lane == owner) sc[m * 65 + owner] = NEGF;
      __syncthreads();
      // cooperative rescan of owner's 256 slots (conflict-free: stride 64)
      float rv = NEGF; int rp = owner * 4;
#pragma unroll
      for (int q = 0; q < 4; ++q) {
        const int mm = lane + q * 64;
        const float s = sc[mm * 65 + owner];
        const int pp = ((mm >> 2) << 8) | (owner << 2) | (mm & 3);
        if (s > rv) { rv = s; rp = pp; }
      }
      wave_argmax(rv, rp);
      if (lane == owner) { hv = rv; hp = rp; }
      __syncthreads();
    }
    __syncthreads();

    // ---- phase 1.5: bulk-fetch boxes of popped candidates ----
    for (int c = lane; c < clen; c += 64) {
      const int p = chunk_p[c];
      boxlist[c] = reinterpret_cast<const float4*>(boxes)[(size_t)b * M_ + p * 4 + cm1];
    }
    __syncthreads();

    // ---- phase 2: serial keep-scan, IoU vs kept list (lanes parallel) ----
    for (int c = 0; c < clen && kept < K_; ++c) {
      const float4 cb = boxlist[c];
      const float x1 = cb.x + offv, y1 = cb.y + offv;
      const float x2 = cb.z + offv, y2 = cb.w + offv;
      const float ab = (x2 - x1) * (y2 - y1);
      bool suppressed = false;
      for (int k0 = 0; k0 < kept; k0 += 64) {
        int s = 0;
        const int ki = k0 + lane;
        if (ki < kept) {
          const float4 kb = keptbox[ki];
          const float ltx = fmaxf(kb.x, x1);
          const float lty = fmaxf(kb.y, y1);
          const float rbx = fminf(kb.z, x2);
          const float rby = fminf(kb.w, y2);
          const float iw = fmaxf(rbx - ltx, 0.f);
          const float ih = fmaxf(rby - lty, 0.f);
          const float inter = iw * ih;
          const float iou = inter / (karea[ki] + ab - inter);  // a1 + a2 - inter
          s = (iou > 0.5f) ? 1 : 0;
        }
        if (__any(s)) { suppressed = true; break; }
      }
      if (!suppressed) {
        if (lane == 0) {
          keptbox[kept] = make_float4(x1, y1, x2, y2);
          karea[kept]   = ab;
          keptpl[kept]  = chunk_p[c];
          keptsl[kept]  = chunk_s[c];
        }
        __syncthreads();
        ++kept;
      }
    }
  }

  for (int i = lane; i < kept; i += 64) {
    g_keptp[task * K_ + i] = keptpl[i];
    g_kepts[task * K_ + i] = keptsl[i];
  }
  if (lane == 0) g_kcount[task] = kept;
}

// ---------------------------------------------------------------------------
// Kernel 3: per-image merge of 4 class keep-lists -> global top-100 by
// (score desc, j asc) via rank counting; gather all outputs.
// ---------------------------------------------------------------------------
__global__ __launch_bounds__(512) void merge_kernel(
    const float* __restrict__ boxes,
    const int*  __restrict__ g_keptp,
    const float* __restrict__ g_kepts,
    const int*  __restrict__ g_kcount,
    const float* __restrict__ handside,  // [N,5]
    const float* __restrict__ dxdymag,   // [N,15]
    const float* __restrict__ contact,   // [N,25]
    float* __restrict__ out)
{
  const int b = blockIdx.x;
  const int t = threadIdx.x;
  __shared__ float ss[400];
  __shared__ int   sj[400];
  __shared__ int   s_total;
  if (t == 0) {
    s_total = g_kcount[b * 4 + 0] + g_kcount[b * 4 + 1] +
              g_kcount[b * 4 + 2] + g_kcount[b * 4 + 3];
  }
  if (t < 400) {
    const int c = t / 100, k = t - c * 100;
    const int task = b * 4 + c;
    const bool valid = k < g_kcount[task];
    ss[t] = valid ? g_kepts[task * K_ + k] : NEGF;
    sj[t] = valid ? (g_keptp[task * K_ + k] * 4 + c) : 0x7FFFFFFF;
  }
  __syncthreads();
  const int total = s_total;

  if (t < 400 && ss[t] > -5e29f) {
    const float sv = ss[t]; const int jv = sj[t];
    int r = 0;
    for (int u = 0; u < 400; ++u) {
      const float su = ss[u]; const int ju = sj[u];
      r += ((su > sv) || (su == sv && ju < jv)) ? 1 : 0;
    }
    if (r < K_) {
      const int j = jv;
      const int p = j >> 2;
      const int cls = (j & 3) + 1;
      const int n = b * P_ + p;
      const float4 bx = reinterpret_cast<const float4*>(boxes)[(size_t)b * M_ + j];
      float bvv = contact[n * 25 + cls * 5 + 0];
      int best = 0;
#pragma unroll
      for (int i = 1; i < 5; ++i) {
        const float ci = contact[n * 25 + cls * 5 + i];
        if (ci > bvv) { bvv = ci; best = i; }
      }
      const int gb = b * K_ + r;
      out[gb * 4 + 0] = bx.x;
      out[gb * 4 + 1] = bx.y;
      out[gb * 4 + 2] = bx.z;
      out[gb * 4 + 3] = bx.w;
      out[3200 + gb] = sv;
      out[4000 + gb] = (float)cls;
      out[4800 + gb] = (handside[n * 5 + cls] > 0.f) ? 1.f : 0.f;
      out[5600 + gb * 3 + 0] = dxdymag[n * 15 + cls * 3 + 0];
      out[5600 + gb * 3 + 1] = dxdymag[n * 15 + cls * 3 + 1];
      out[5600 + gb * 3 + 2] = dxdymag[n * 15 + cls * 3 + 2];
      out[8000 + gb] = (float)best;
      out[8800 + gb] = 1.f;
    }
  }

  if (t >= 400 && t < 400 + K_) {
    const int r = t - 400;
    if (r >= total) {   // zero-fill empty slots (total>=100 -> none)
      const int gb = b * K_ + r;
      out[gb * 4 + 0] = 0.f; out[gb * 4 + 1] = 0.f;
      out[gb * 4 + 2] = 0.f; out[gb * 4 + 3] = 0.f;
      out[3200 + gb] = 0.f;
      out[4000 + gb] = 0.f;
      out[4800 + gb] = 0.f;
      out[5600 + gb * 3 + 0] = 0.f;
      out[5600 + gb * 3 + 1] = 0.f;
      out[5600 + gb * 3 + 2] = 0.f;
      out[8000 + gb] = 0.f;
      out[8800 + gb] = 0.f;
    }
  }
}

// ---------------------------------------------------------------------------
extern "C" void kernel_launch(void* const* d_in, const int* in_sizes, int n_in,
                              void* d_out, int out_size, void* d_ws, size_t ws_size,
                              hipStream_t stream) {
  const float* class_logits = (const float*)d_in[0];
  const float* box_reg      = (const float*)d_in[1];
  const float* handside     = (const float*)d_in[2];
  const float* dxdymag      = (const float*)d_in[3];
  const float* contact      = (const float*)d_in[4];
  const float* proposals    = (const float*)d_in[5];
  const int*   image_hw     = (const int*)d_in[6];
  float* out = (float*)d_out;

  char* ws = (char*)d_ws;
  float* wboxes   = (float*)ws;                               // 8 MiB
  float* wscoresT = (float*)(ws + (size_t)8  * 1024 * 1024);  // 2 MiB
  int*   wmax     = (int*)  (ws + (size_t)10 * 1024 * 1024);  // 32 B
  int*   g_keptp  = (int*)  (ws + (size_t)10 * 1024 * 1024 + 1024);
  float* g_kepts  = (float*)(ws + (size_t)10 * 1024 * 1024 + 1024 + 32 * K_ * 4);
  int*   g_kcount = (int*)  (ws + (size_t)10 * 1024 * 1024 + 1024 + 64 * K_ * 4);

  hipMemsetAsync(wmax, 0, B_ * sizeof(int), stream);
  prep_kernel<<<dim3(512), dim3(256), 0, stream>>>(
      class_logits, box_reg, proposals, image_hw, wboxes, wscoresT, wmax);
  nms_class_kernel<<<dim3(32), dim3(64), 0, stream>>>(
      wboxes, wscoresT, wmax, g_keptp, g_kepts, g_kcount);
  merge_kernel<<<dim3(B_), dim3(512), 0, stream>>>(
      wboxes, g_keptp, g_kepts, g_kcount, handside, dxdymag, contact, out);
}

// Round 3
// 168.385 us; speedup vs baseline: 5.8436x; 1.4196x over previous
//
#include <hip/hip_runtime.h>
#include <cstdint>

typedef unsigned int u32;
typedef unsigned long long u64;
typedef unsigned char u8;

constexpr int B_ = 8;
constexpr int P_ = 16384;
constexpr int K_ = 100;
constexpr int M_ = P_ * 4;          // 65536 candidates per image, j = p*4 + (cls-1)
constexpr int TSEL = 256;           // selection chunk target size
constexpr int CAP = 512;            // selection capacity (sorted per chunk)
constexpr int SUB = 256;            // resolve sub-chunk (bitmask width)
constexpr float NEGF = -1e30f;
constexpr float SCORE_T = 0.05f;
constexpr float CLIPV = 4.135166556742356f;  // log(1000/16)

// ---------------------------------------------------------------------------
// Kernel 1: softmax + decode + clip. boxes [B*M,4] and scores [B*M] in j-order
// (NEG-masked below 0.05); per-image max coordinate via atomicMax on f32 bits.
// ---------------------------------------------------------------------------
__global__ __launch_bounds__(256) void prep_kernel(
    const float* __restrict__ logits,     // [N,5]
    const float* __restrict__ boxreg,     // [N,20]
    const float* __restrict__ props,      // [N,4]
    const int*  __restrict__ image_hw,    // {H, W}
    float* __restrict__ wboxes,           // [B*M,4]
    float* __restrict__ wscores,          // [B*M]
    int*   __restrict__ wmax)             // [B]
{
  const int n = blockIdx.x * 256 + threadIdx.x;   // 512*256 == B*P

  float l[5];
#pragma unroll
  for (int i = 0; i < 5; ++i) l[i] = logits[n * 5 + i];
  float mx = l[0];
#pragma unroll
  for (int i = 1; i < 5; ++i) mx = fmaxf(mx, l[i]);
  float e[5]; float ssum = 0.f;
#pragma unroll
  for (int i = 0; i < 5; ++i) { e[i] = expf(l[i] - mx); ssum += e[i]; }

  const float4 pr = reinterpret_cast<const float4*>(props)[n];
  const float w  = pr.z - pr.x;
  const float h  = pr.w - pr.y;
  const float cx = pr.x + 0.5f * w;
  const float cy = pr.y + 0.5f * h;
  const float Hf = (float)image_hw[0];
  const float Wf = (float)image_hw[1];

  float bmax = 0.f;
  float sc[4];
#pragma unroll
  for (int c = 1; c < 5; ++c) {
    const float4 rel = reinterpret_cast<const float4*>(boxreg)[n * 5 + c];
    const float dx = rel.x / 10.0f;
    const float dy = rel.y / 10.0f;
    const float dw = fminf(rel.z / 5.0f, CLIPV);
    const float dh = fminf(rel.w / 5.0f, CLIPV);
    const float pcx = dx * w + cx;
    const float pcy = dy * h + cy;
    const float pw = expf(dw) * w;
    const float ph = expf(dh) * h;
    float x1 = pcx - 0.5f * pw, y1 = pcy - 0.5f * ph;
    float x2 = pcx + 0.5f * pw, y2 = pcy + 0.5f * ph;
    x1 = fminf(fmaxf(x1, 0.f), Wf);
    x2 = fminf(fmaxf(x2, 0.f), Wf);
    y1 = fminf(fmaxf(y1, 0.f), Hf);
    y2 = fminf(fmaxf(y2, 0.f), Hf);
    reinterpret_cast<float4*>(wboxes)[n * 4 + (c - 1)] = make_float4(x1, y1, x2, y2);
    bmax = fmaxf(bmax, fmaxf(fmaxf(x1, x2), fmaxf(y1, y2)));
    const float scv = e[c] / ssum;
    sc[c - 1] = (scv > SCORE_T) ? scv : NEGF;
  }
  reinterpret_cast<float4*>(wscores)[n] = make_float4(sc[0], sc[1], sc[2], sc[3]);

  __shared__ float red[256];
  red[threadIdx.x] = bmax;
  __syncthreads();
#pragma unroll
  for (int off = 128; off > 0; off >>= 1) {
    if (threadIdx.x < off) red[threadIdx.x] = fmaxf(red[threadIdx.x], red[threadIdx.x + off]);
    __syncthreads();
  }
  if (threadIdx.x == 0) atomicMax(&wmax[n >> 14], __float_as_int(red[0]));
}

// ---------------------------------------------------------------------------
// Kernel 2: per-image selection (two-level radix on score bits) + bitonic sort
// of top chunk + bitmask greedy resolve + output gather. One 512-thread block
// per image. Valid scores lie in (0.05, 1) -> f32 bits>>22 in [245, 253].
// ---------------------------------------------------------------------------
__global__ __launch_bounds__(512) void nms_image_kernel(
    const float* __restrict__ boxes,     // [B*M,4]
    const float* __restrict__ scores,    // [B*M] j-order, NEG-masked
    const int*  __restrict__ wmax,       // [B]
    const float* __restrict__ handside,  // [N,5]
    const float* __restrict__ dxdymag,   // [N,15]
    const float* __restrict__ contact,   // [N,25]
    float* __restrict__ out)             // 9600 floats
{
  const int b = blockIdx.x;
  const int t = threadIdx.x;
  const float maxv1 = __int_as_float(wmax[b]) + 1.0f;   // boxes.max() + 1.0
  const float4* boxes4 = reinterpret_cast<const float4*>(boxes);
  const float4* sc4 = reinterpret_cast<const float4*>(scores) + (size_t)b * (M_ / 4);

  __shared__ u32 hist1[16];           // 9 active exponent-ish buckets
  __shared__ u32 hist2[4096];
  __shared__ u32 part2[512];
  __shared__ u64 keys[CAP];
  __shared__ int sel_n;
  __shared__ int C_s, need2_s, b1_s, cumA1_s, tot_s, rem_s, brk_s;
  __shared__ u32 X_s, ub_s;
  // candidates (current resolve sub-chunk)
  __shared__ float cox1[SUB], coy1[SUB], cox2[SUB], coy2[SUB], carea[SUB];
  __shared__ float4 cbx[SUB];
  __shared__ float csc[SUB];
  __shared__ int   cj[SUB];
  __shared__ u8    killed[SUB];
  __shared__ u64   supmask[SUB * 4];
  // kept (global greedy keeps, in order)
  __shared__ float kox1[K_], koy1[K_], kox2[K_], koy2[K_], karea[K_];
  __shared__ float4 kbx[K_];
  __shared__ float ksc[K_];
  __shared__ int   kj_s[K_];
  __shared__ int   kcount_s;

  if (t == 0) { kcount_s = 0; ub_s = 0xFFFFFFFFu; brk_s = 0; }
  __syncthreads();

  while (true) {
    const u32 ub = ub_s;   // exclusive upper bound on score bits

    // ---- pass 1: L1 histogram via register counters (no contention) ----
    if (t < 16) hist1[t] = 0;
    __syncthreads();
    {
      u32 cnt[9] = {0, 0, 0, 0, 0, 0, 0, 0, 0};
      for (int i = t; i < M_ / 4; i += 512) {
        const float4 v = sc4[i];
        const float ss[4] = {v.x, v.y, v.z, v.w};
#pragma unroll
        for (int c = 0; c < 4; ++c) {
          const float s = ss[c];
          if (s > 0.f) {
            const u32 bb = __float_as_uint(s);
            if (bb < ub) {
              const int bi = (int)(bb >> 22) - 245;   // in [0,8] for (0.05,1)
#pragma unroll
              for (int q = 0; q < 9; ++q) cnt[q] += (bi == q) ? 1u : 0u;
            }
          }
        }
      }
#pragma unroll
      for (int q = 0; q < 9; ++q) if (cnt[q]) atomicAdd(&hist1[q], cnt[q]);
    }
    __syncthreads();
    if (t == 0) {
      int cum = 0, b1i = -1, cumA1 = 0;
      for (int q = 8; q >= 0; --q) {
        const int h = (int)hist1[q];
        if (b1i < 0 && cum + h >= TSEL) { b1i = q; cumA1 = cum; }
        cum += h;
      }
      if (cum == 0) { brk_s = 1; }
      else if (b1i < 0) { need2_s = 0; C_s = cum; X_s = 0u; rem_s = 0; }  // tail: all remain
      else { need2_s = 1; b1_s = 245 + b1i; cumA1_s = cumA1; tot_s = cum; }
    }
    __syncthreads();
    if (brk_s) break;

    if (need2_s) {
      const u32 b1 = (u32)b1_s;
      // ---- pass 2: L2 histogram (bits [21:10]) within bucket b1 ----
      for (int i = t; i < 4096; i += 512) hist2[i] = 0;
      __syncthreads();
      for (int i = t; i < M_ / 4; i += 512) {
        const float4 v = sc4[i];
        const float ss[4] = {v.x, v.y, v.z, v.w};
#pragma unroll
        for (int c = 0; c < 4; ++c) {
          const float s = ss[c];
          if (s > 0.f) {
            const u32 bb = __float_as_uint(s);
            if (bb < ub && (bb >> 22) == b1) atomicAdd(&hist2[(bb >> 10) & 0xFFFu], 1u);
          }
        }
      }
      __syncthreads();
      {
        u32 ps = 0;
#pragma unroll
        for (int q = 0; q < 8; ++q) ps += hist2[t * 8 + q];
        part2[t] = ps;
      }
      __syncthreads();
      if (t == 0) {
        const int T2 = TSEL - cumA1_s;     // >= 1
        int cum2 = 0, b2 = 0;
        for (int pi = 511; pi >= 0; --pi) {
          const int ps = (int)part2[pi];
          if (cum2 + ps >= T2) {
            for (int q = 7; q >= 0; --q) {
              const int idx = pi * 8 + q;
              const int hv = (int)hist2[idx];
              if (cum2 + hv >= T2) { b2 = idx; cum2 += hv; break; }
              cum2 += hv;
            }
            break;
          }
          cum2 += ps;
        }
        int C = cumA1_s + cum2;
        u32 X = ((u32)b1_s << 22) | ((u32)b2 << 10);
        if (C > CAP) {                     // massive 22-bit-prefix tie: exclude boundary bucket
          C -= (int)hist2[b2];
          X += (1u << 10);                 // carries into b1 bits correctly if b2==4095
        }
        if (C <= 0) brk_s = 1;             // unreachable in practice; prevents stall
        C_s = C; X_s = X; rem_s = tot_s - C;
      }
      __syncthreads();
      if (brk_s) break;
    }

    // ---- pass 3: compact candidates with bits in [X, ub) ----
    keys[t] = 0ull;                        // CAP == blockDim
    if (t == 0) sel_n = 0;
    __syncthreads();
    {
      const u32 X = X_s;
      for (int i = t; i < M_ / 4; i += 512) {
        const float4 v = sc4[i];
        const float ss[4] = {v.x, v.y, v.z, v.w};
        const int j0 = i * 4;
#pragma unroll
        for (int c = 0; c < 4; ++c) {
          const float s = ss[c];
          if (s > 0.f) {
            const u32 bb = __float_as_uint(s);
            if (bb < ub && bb >= X) {
              const int pos = atomicAdd(&sel_n, 1);
              if (pos < CAP)
                keys[pos] = ((u64)bb << 16) | (u64)(65535 - (j0 + c));
            }
          }
        }
      }
    }
    __syncthreads();

    // ---- bitonic sort, descending by key = (score_bits, 65535-j) ----
    for (int k = 2; k <= CAP; k <<= 1) {
      for (int jj = k >> 1; jj > 0; jj >>= 1) {
        const int p = t ^ jj;
        if (p > t) {
          const u64 a = keys[t], bk = keys[p];
          const bool desc = ((t & k) == 0);
          if (desc ? (a < bk) : (a > bk)) { keys[t] = bk; keys[p] = a; }
        }
        __syncthreads();
      }
    }

    // ---- resolve in sub-chunks of 256 (exact greedy order) ----
    const int C = C_s;
    for (int s0 = 0; s0 < C; s0 += SUB) {
      const int S = min(SUB, C - s0);
      if (t < S) {
        const u64 key = keys[s0 + t];
        const int j = 65535 - (int)(key & 0xFFFFull);
        const float4 bx = boxes4[b * M_ + j];
        const float offv = (float)((j & 3) + 1) * maxv1;   // label * (max+1)
        const float x1 = bx.x + offv, y1 = bx.y + offv;
        const float x2 = bx.z + offv, y2 = bx.w + offv;
        const float ar = (x2 - x1) * (y2 - y1);
        cox1[t] = x1; coy1[t] = y1; cox2[t] = x2; coy2[t] = y2; carea[t] = ar;
        cbx[t] = bx;
        csc[t] = __uint_as_float((u32)(key >> 16));
        cj[t] = j;
        u8 kd = 0;
        const int kc = kcount_s;
        for (int k2 = 0; k2 < kc; ++k2) {   // suppressed by an earlier keep?
          const float ltx = fmaxf(kox1[k2], x1);
          const float lty = fmaxf(koy1[k2], y1);
          const float rbx = fminf(kox2[k2], x2);
          const float rby = fminf(koy2[k2], y2);
          const float iw = fmaxf(rbx - ltx, 0.f);
          const float ih = fmaxf(rby - lty, 0.f);
          const float inter = iw * ih;
          const float iou = inter / (karea[k2] + ar - inter);  // a1+a2-inter
          if (iou > 0.5f) { kd = 1; break; }
        }
        killed[t] = kd;
      }
      __syncthreads();
      // pairwise suppression bitmasks among the sub-chunk
      for (int task = t; task < S * 4; task += 512) {
        const int i = task >> 2, w = task & 3;
        const float ix1 = cox1[i], iy1 = coy1[i], ix2 = cox2[i], iy2 = coy2[i], ia = carea[i];
        u64 m = 0;
        const int jb = w * 64;
        const int je = min(jb + 64, S);
        for (int q = jb; q < je; ++q) {
          const float ltx = fmaxf(ix1, cox1[q]);
          const float lty = fmaxf(iy1, coy1[q]);
          const float rbx = fminf(ix2, cox2[q]);
          const float rby = fminf(iy2, coy2[q]);
          const float iw = fmaxf(rbx - ltx, 0.f);
          const float ih = fmaxf(rby - lty, 0.f);
          const float inter = iw * ih;
          const float iou = inter / (ia + carea[q] - inter);
          if (iou > 0.5f) m |= 1ull << (q - jb);   // NaN -> false (matches ref)
        }
        supmask[i * 4 + w] = m;
      }
      __syncthreads();
      if (t == 0) {
        u64 a0 = ~0ull, a1 = ~0ull, a2 = ~0ull, a3 = ~0ull;
        int kc = kcount_s;
        for (int i = 0; i < S && kc < K_; ++i) {
          const u64 aw = (i < 64) ? a0 : (i < 128) ? a1 : (i < 192) ? a2 : a3;
          if (!((aw >> (i & 63)) & 1ull)) continue;
          if (killed[i]) continue;
          kox1[kc] = cox1[i]; koy1[kc] = coy1[i]; kox2[kc] = cox2[i]; koy2[kc] = coy2[i];
          karea[kc] = carea[i]; kbx[kc] = cbx[i]; ksc[kc] = csc[i]; kj_s[kc] = cj[i];
          ++kc;
          a0 &= ~supmask[i * 4 + 0];
          a1 &= ~supmask[i * 4 + 1];
          a2 &= ~supmask[i * 4 + 2];
          a3 &= ~supmask[i * 4 + 3];
        }
        kcount_s = kc;
      }
      __syncthreads();
      if (kcount_s >= K_) break;
    }

    if (kcount_s >= K_ || rem_s == 0) break;
    if (t == 0) ub_s = X_s;                 // next chunk: strictly below this chunk
    __syncthreads();
  }
  __syncthreads();

  // ---- output gather: threads 0..99 write one slot each; zeros past kcount ----
  const int kc = kcount_s;
  if (t < K_) {
    const int r = t;
    float ob0 = 0.f, ob1 = 0.f, ob2 = 0.f, ob3 = 0.f;
    float osc = 0.f, olab = 0.f, oside = 0.f;
    float od0 = 0.f, od1 = 0.f, od2 = 0.f;
    float ocon = 0.f, okeep = 0.f;
    if (r < kc) {
      const int j = kj_s[r];
      const int p = j >> 2;
      const int cls = (j & 3) + 1;
      const int n = b * P_ + p;
      const float4 bx = kbx[r];
      ob0 = bx.x; ob1 = bx.y; ob2 = bx.z; ob3 = bx.w;
      osc = ksc[r];
      olab = (float)cls;
      oside = (handside[n * 5 + cls] > 0.f) ? 1.f : 0.f;    // sigmoid>0.5 <=> x>0
      od0 = dxdymag[n * 15 + cls * 3 + 0];
      od1 = dxdymag[n * 15 + cls * 3 + 1];
      od2 = dxdymag[n * 15 + cls * 3 + 2];
      float bvv = contact[n * 25 + cls * 5 + 0];
      int best = 0;
#pragma unroll
      for (int i = 1; i < 5; ++i) {
        const float ci = contact[n * 25 + cls * 5 + i];
        if (ci > bvv) { bvv = ci; best = i; }
      }
      ocon = (float)best;
      okeep = 1.f;
    }
    const int gb = b * K_ + r;
    out[gb * 4 + 0] = ob0;
    out[gb * 4 + 1] = ob1;
    out[gb * 4 + 2] = ob2;
    out[gb * 4 + 3] = ob3;
    out[3200 + gb] = osc;
    out[4000 + gb] = olab;
    out[4800 + gb] = oside;
    out[5600 + gb * 3 + 0] = od0;
    out[5600 + gb * 3 + 1] = od1;
    out[5600 + gb * 3 + 2] = od2;
    out[8000 + gb] = ocon;
    out[8800 + gb] = okeep;
  }
}

// ---------------------------------------------------------------------------
extern "C" void kernel_launch(void* const* d_in, const int* in_sizes, int n_in,
                              void* d_out, int out_size, void* d_ws, size_t ws_size,
                              hipStream_t stream) {
  const float* class_logits = (const float*)d_in[0];
  const float* box_reg      = (const float*)d_in[1];
  const float* handside     = (const float*)d_in[2];
  const float* dxdymag      = (const float*)d_in[3];
  const float* contact      = (const float*)d_in[4];
  const float* proposals    = (const float*)d_in[5];
  const int*   image_hw     = (const int*)d_in[6];
  float* out = (float*)d_out;

  char* ws = (char*)d_ws;
  float* wboxes  = (float*)ws;                               // 8 MiB
  float* wscores = (float*)(ws + (size_t)8  * 1024 * 1024);  // 2 MiB
  int*   wmax    = (int*)  (ws + (size_t)10 * 1024 * 1024);  // 32 B

  hipMemsetAsync(wmax, 0, B_ * sizeof(int), stream);
  prep_kernel<<<dim3(512), dim3(256), 0, stream>>>(
      class_logits, box_reg, proposals, image_hw, wboxes, wscores, wmax);
  nms_image_kernel<<<dim3(B_), dim3(512), 0, stream>>>(
      wboxes, wscores, wmax, handside, dxdymag, contact, out);
}

// Round 4
// 106.294 us; speedup vs baseline: 9.2572x; 1.5841x over previous
//
#include <hip/hip_runtime.h>
#include <cstdint>

typedef unsigned int u32;
typedef unsigned long long u64;
typedef unsigned char u8;

constexpr int B_ = 8;
constexpr int P_ = 16384;
constexpr int K_ = 100;
constexpr int TSEL = 256;           // selection target
constexpr int CAP = 512;            // selection capacity
constexpr int SUB = 256;            // resolve sub-chunk
constexpr int NBPAD = 9216;         // histogram bins (padded), bits>>12 based
constexpr u32 BASE12 = 0x3D4CCu;    // (bits(0.05f)+1)>>12
constexpr float SCORE_T = 0.05f;
constexpr float CLIPV = 4.135166556742356f;  // log(1000/16)

// ---------------------------------------------------------------------------
// Kernel 1 (wide): softmax + decode (for per-image max coord only) + global
// per-image histogram of score bits (>>12). No bulk stores.
// ---------------------------------------------------------------------------
__global__ __launch_bounds__(256) void prep_kernel(
    const float* __restrict__ logits,     // [N,5]
    const float* __restrict__ boxreg,     // [N,20]
    const float* __restrict__ props,      // [N,4]
    const int*  __restrict__ image_hw,    // {H,W}
    u32* __restrict__ hist,               // [B*NBPAD]
    int* __restrict__ wmax)               // [B]
{
  const int n = blockIdx.x * 256 + threadIdx.x;   // 512*256 == B*P
  const int b = n >> 14;

  float l[5];
#pragma unroll
  for (int i = 0; i < 5; ++i) l[i] = logits[n * 5 + i];
  float mx = l[0];
#pragma unroll
  for (int i = 1; i < 5; ++i) mx = fmaxf(mx, l[i]);
  float e[5]; float ssum = 0.f;
#pragma unroll
  for (int i = 0; i < 5; ++i) { e[i] = expf(l[i] - mx); ssum += e[i]; }

  const float4 pr = reinterpret_cast<const float4*>(props)[n];
  const float w  = pr.z - pr.x;
  const float h  = pr.w - pr.y;
  const float cx = pr.x + 0.5f * w;
  const float cy = pr.y + 0.5f * h;
  const float Hf = (float)image_hw[0];
  const float Wf = (float)image_hw[1];

  float bmax = 0.f;
#pragma unroll
  for (int c = 1; c < 5; ++c) {
    const float4 rel = reinterpret_cast<const float4*>(boxreg)[n * 5 + c];
    const float dx = rel.x / 10.0f;
    const float dy = rel.y / 10.0f;
    const float dw = fminf(rel.z / 5.0f, CLIPV);
    const float dh = fminf(rel.w / 5.0f, CLIPV);
    const float pcx = dx * w + cx;
    const float pcy = dy * h + cy;
    const float pw = expf(dw) * w;
    const float ph = expf(dh) * h;
    float x1 = pcx - 0.5f * pw, y1 = pcy - 0.5f * ph;
    float x2 = pcx + 0.5f * pw, y2 = pcy + 0.5f * ph;
    x1 = fminf(fmaxf(x1, 0.f), Wf);
    x2 = fminf(fmaxf(x2, 0.f), Wf);
    y1 = fminf(fmaxf(y1, 0.f), Hf);
    y2 = fminf(fmaxf(y2, 0.f), Hf);
    bmax = fmaxf(bmax, fmaxf(fmaxf(x1, x2), fmaxf(y1, y2)));
    const float s = e[c] / ssum;
    if (s > SCORE_T) {
      const u32 bb = __float_as_uint(s);
      u32 bin = (bb >> 12) - BASE12;
      if (bin > (u32)(NBPAD - 1)) bin = NBPAD - 1;
      atomicAdd(&hist[b * NBPAD + bin], 1u);
    }
  }

  __shared__ float red[256];
  red[threadIdx.x] = bmax;
  __syncthreads();
#pragma unroll
  for (int off = 128; off > 0; off >>= 1) {
    if (threadIdx.x < off) red[threadIdx.x] = fmaxf(red[threadIdx.x], red[threadIdx.x + off]);
    __syncthreads();
  }
  if (threadIdx.x == 0) atomicMax(&wmax[b], __float_as_int(red[0]));
}

// ---------------------------------------------------------------------------
// Kernel 2: per-image threshold from histogram. X such that count(bb>=X) = C,
// TSEL <= C <= CAP (or C = tot when tot < TSEL). rem = tot - C.
// ---------------------------------------------------------------------------
__global__ __launch_bounds__(512) void thresh_kernel(
    const u32* __restrict__ hist, u32* __restrict__ Xthr, int* __restrict__ remv)
{
  const int b = blockIdx.x, t = threadIdx.x;
  const u32* h = hist + b * NBPAD;
  const int hi = NBPAD - t * 18, lo = hi - 18;   // t=0 owns the TOP 18 bins
  u32 hb[18]; int mysum = 0;
#pragma unroll
  for (int q = 0; q < 18; ++q) { hb[q] = h[lo + q]; mysum += (int)hb[q]; }

  __shared__ int part[512];
  part[t] = mysum;
  __syncthreads();
  for (int off = 1; off < 512; off <<= 1) {       // inclusive scan, thread order
    const int v = (t >= off) ? part[t - off] : 0;
    __syncthreads();
    part[t] += v;
    __syncthreads();
  }
  const int inc = part[t];
  const int pre = inc - mysum;                     // count in chunks above
  const int tot = part[511];

  if (tot < TSEL) {
    if (t == 0) { Xthr[b] = BASE12 << 12; remv[b] = 0; }
    return;
  }
  if (pre < TSEL && inc >= TSEL) {                 // boundary chunk (unique)
    int cum = pre, k = hi - 1;
    for (int q = 17; q >= 0; --q) {                // top bin of chunk first
      cum += (int)hb[q];
      if (cum >= TSEL) { k = lo + q; break; }
    }
    int C = cum;
    u32 Xbin;
    if (C > CAP) { C -= (int)h[k]; Xbin = (u32)(k + 1); }  // count above bin < TSEL
    else Xbin = (u32)k;
    Xthr[b] = (BASE12 + Xbin) << 12;
    remv[b] = tot - C;
  }
}

// ---------------------------------------------------------------------------
// Kernel 3 (wide): recompute softmax, append keys for bb >= X.
// Order nondeterministic; dedup'd by exact sort in kernel 4. count == C.
// ---------------------------------------------------------------------------
__global__ __launch_bounds__(256) void compact_kernel(
    const float* __restrict__ logits, const u32* __restrict__ Xthr,
    int* __restrict__ selcnt, u64* __restrict__ keybuf)
{
  const int n = blockIdx.x * 256 + threadIdx.x;
  const int b = n >> 14;
  const int p = n & (P_ - 1);
  const u32 X = Xthr[b];

  float l[5];
#pragma unroll
  for (int i = 0; i < 5; ++i) l[i] = logits[n * 5 + i];
  float mx = l[0];
#pragma unroll
  for (int i = 1; i < 5; ++i) mx = fmaxf(mx, l[i]);
  float e[5]; float ssum = 0.f;
#pragma unroll
  for (int i = 0; i < 5; ++i) { e[i] = expf(l[i] - mx); ssum += e[i]; }

#pragma unroll
  for (int c = 1; c < 5; ++c) {
    const float s = e[c] / ssum;
    if (s > SCORE_T) {
      const u32 bb = __float_as_uint(s);
      if (bb >= X) {
        const int j = p * 4 + (c - 1);
        const int pos = atomicAdd(&selcnt[b], 1);
        if (pos < CAP) keybuf[b * CAP + pos] = ((u64)bb << 16) | (u64)(65535 - j);
      }
    }
  }
}

// ---------------------------------------------------------------------------
// Kernel 4: per-image NMS on <=512 candidates. rank-sort + decode + bitmask
// greedy resolve + gather. Slow-path continuation for exactness (never taken
// on benign data).
// ---------------------------------------------------------------------------
__global__ __launch_bounds__(512) void nms_kernel(
    const float* __restrict__ logits, const float* __restrict__ boxreg,
    const float* __restrict__ props, const int* __restrict__ image_hw,
    const int* __restrict__ wmax, const u32* __restrict__ Xthr,
    const int* __restrict__ remv, const int* __restrict__ selcnt,
    const u64* __restrict__ keybuf,
    const float* __restrict__ handside, const float* __restrict__ dxdymag,
    const float* __restrict__ contact, float* __restrict__ out)
{
  const int b = blockIdx.x, t = threadIdx.x;
  const float maxv1 = __int_as_float(wmax[b]) + 1.0f;
  const float Hf = (float)image_hw[0];
  const float Wf = (float)image_hw[1];
  const u32 X = Xthr[b];
  int C = selcnt[b]; if (C > CAP) C = CAP;

  __shared__ u64 kall[CAP];
  __shared__ u64 skey[CAP];
  __shared__ float cox1[CAP + K_], coy1[CAP + K_], cox2[CAP + K_], coy2[CAP + K_];
  __shared__ float carea[CAP + K_], cscf[CAP + K_];
  __shared__ float4 cbx[CAP + K_];
  __shared__ int   cj[CAP + K_];
  __shared__ u8    killed[SUB];
  __shared__ u32   flagpack[SUB / 4];
  __shared__ u64   supmask[SUB * 4];
  __shared__ int   kidx[K_];
  __shared__ int   kcount_s, nslow_s;
  __shared__ u64   bitmap[1024];

  if (t == 0) { kcount_s = 0; nslow_s = 0; }
  kall[t] = (t < C) ? keybuf[b * CAP + t] : 0ull;
  __syncthreads();

  // rank-by-counting sort (keys unique among valid; zeros sink)
  {
    const u64 mykey = kall[t];
    u32 r = 0;
    for (int u = 0; u < CAP; ++u) r += (kall[u] > mykey) ? 1u : 0u;
    if (t < C) skey[r] = mykey;
  }
  __syncthreads();

  // decode candidates (bit-identical to reference op order)
  if (t < C) {
    const u64 key = skey[t];
    const int j = 65535 - (int)(key & 0xFFFFull);
    const int cls = (j & 3) + 1;
    const int n = b * P_ + (j >> 2);
    const float4 rel = reinterpret_cast<const float4*>(boxreg)[n * 5 + cls];
    const float4 pr  = reinterpret_cast<const float4*>(props)[n];
    const float w  = pr.z - pr.x;
    const float h  = pr.w - pr.y;
    const float cx = pr.x + 0.5f * w;
    const float cy = pr.y + 0.5f * h;
    const float dx = rel.x / 10.0f;
    const float dy = rel.y / 10.0f;
    const float dw = fminf(rel.z / 5.0f, CLIPV);
    const float dh = fminf(rel.w / 5.0f, CLIPV);
    const float pcx = dx * w + cx;
    const float pcy = dy * h + cy;
    const float pw = expf(dw) * w;
    const float ph = expf(dh) * h;
    float x1 = pcx - 0.5f * pw, y1 = pcy - 0.5f * ph;
    float x2 = pcx + 0.5f * pw, y2 = pcy + 0.5f * ph;
    x1 = fminf(fmaxf(x1, 0.f), Wf);
    x2 = fminf(fmaxf(x2, 0.f), Wf);
    y1 = fminf(fmaxf(y1, 0.f), Hf);
    y2 = fminf(fmaxf(y2, 0.f), Hf);
    const float offv = (float)cls * maxv1;
    const float ox1 = x1 + offv, oy1 = y1 + offv;
    const float ox2 = x2 + offv, oy2 = y2 + offv;
    cox1[t] = ox1; coy1[t] = oy1; cox2[t] = ox2; coy2[t] = oy2;
    carea[t] = (ox2 - ox1) * (oy2 - oy1);
    cbx[t] = make_float4(x1, y1, x2, y2);
    cscf[t] = __uint_as_float((u32)(key >> 16));
    cj[t] = j;
  }
  __syncthreads();

  // ---- resolve in sub-chunks ----
  for (int s0 = 0; s0 < C; s0 += SUB) {
    const int S = min(SUB, C - s0);
    // killed vs keeps so far (broadcast reads via kidx indirection)
    if (t < S) {
      const float ax1 = cox1[s0 + t], ay1 = coy1[s0 + t];
      const float ax2 = cox2[s0 + t], ay2 = coy2[s0 + t];
      const float ar = carea[s0 + t];
      u8 kd = 0;
      const int kc0 = kcount_s;
      for (int k2 = 0; k2 < kc0; ++k2) {
        const int ki = kidx[k2];
        const float ltx = fmaxf(cox1[ki], ax1);
        const float lty = fmaxf(coy1[ki], ay1);
        const float rbx = fminf(cox2[ki], ax2);
        const float rby = fminf(coy2[ki], ay2);
        const float iw = fmaxf(rbx - ltx, 0.f);
        const float ih = fmaxf(rby - lty, 0.f);
        const float inter = iw * ih;
        const float iou = inter / (carea[ki] + ar - inter);
        if (iou > 0.5f) { kd = 1; break; }
      }
      killed[t] = kd;
    }
    // pairwise masks (self excluded)
    for (int task = t; task < S * 4; task += 512) {
      const int i = task >> 2, wq = task & 3;
      const float ix1 = cox1[s0 + i], iy1 = coy1[s0 + i];
      const float ix2 = cox2[s0 + i], iy2 = coy2[s0 + i];
      const float ia = carea[s0 + i];
      u64 m = 0;
      const int qb = wq * 64, qe = min(qb + 64, S);
      for (int q = qb; q < qe; ++q) {
        if (q == i) continue;
        const float ltx = fmaxf(ix1, cox1[s0 + q]);
        const float lty = fmaxf(iy1, coy1[s0 + q]);
        const float rbx = fminf(ix2, cox2[s0 + q]);
        const float rby = fminf(iy2, coy2[s0 + q]);
        const float iw = fmaxf(rbx - ltx, 0.f);
        const float ih = fmaxf(rby - lty, 0.f);
        const float inter = iw * ih;
        const float iou = inter / (ia + carea[s0 + q] - inter);
        if (iou > 0.5f) m |= 1ull << (q - qb);
      }
      supmask[i * 4 + wq] = m;
    }
    __syncthreads();
    // pack killed|anysup, 4 candidates per u32
    if (t < SUB / 4) {
      u32 v = 0;
#pragma unroll
      for (int q = 0; q < 4; ++q) {
        const int i = t * 4 + q;
        if (i < S) {
          const u64 o = supmask[i * 4] | supmask[i * 4 + 1] |
                        supmask[i * 4 + 2] | supmask[i * 4 + 3];
          const u32 fl = (u32)killed[i] | ((o != 0ull) ? 2u : 0u);
          v |= fl << (q * 8);
        }
      }
      flagpack[t] = v;
    }
    __syncthreads();
    // serial walk (thread 0): ~26 dependent LDS reads typical
    if (t == 0) {
      u64 a0 = ~0ull, a1 = ~0ull, a2 = ~0ull, a3 = ~0ull;
      int kc = kcount_s;
      for (int i0 = 0; i0 < S && kc < K_; i0 += 4) {
        const u32 f4 = flagpack[i0 >> 2];
#pragma unroll
        for (int q = 0; q < 4; ++q) {
          const int i = i0 + q;
          if (i >= S || kc >= K_) break;
          const u32 fl = (f4 >> (q * 8)) & 0xFFu;
          const u64 aw = (i < 64) ? a0 : (i < 128) ? a1 : (i < 192) ? a2 : a3;
          if (((aw >> (i & 63)) & 1ull) && !(fl & 1u)) {
            kidx[kc++] = s0 + i;
            if (fl & 2u) {
              a0 &= ~supmask[i * 4 + 0];
              a1 &= ~supmask[i * 4 + 1];
              a2 &= ~supmask[i * 4 + 2];
              a3 &= ~supmask[i * 4 + 3];
            }
          }
        }
      }
      kcount_s = kc;
    }
    __syncthreads();
    if (kcount_s >= K_) break;
  }

  // ---- slow-path continuation (exactness; never taken on benign data) ----
  if (kcount_s < K_ && remv[b] > 0) {
    for (int i = t; i < 1024; i += 512) bitmap[i] = 0ull;
    __syncthreads();
    while (true) {
      u64 best = 0ull;
      for (int p = t; p < P_; p += 512) {
        const int n = b * P_ + p;
        float l[5];
#pragma unroll
        for (int i = 0; i < 5; ++i) l[i] = logits[n * 5 + i];
        float mxl = l[0];
#pragma unroll
        for (int i = 1; i < 5; ++i) mxl = fmaxf(mxl, l[i]);
        float e[5]; float ssum = 0.f;
#pragma unroll
        for (int i = 0; i < 5; ++i) { e[i] = expf(l[i] - mxl); ssum += e[i]; }
#pragma unroll
        for (int c = 1; c < 5; ++c) {
          const float s = e[c] / ssum;
          if (s > SCORE_T) {
            const u32 bb = __float_as_uint(s);
            if (bb < X) {
              const int j = p * 4 + (c - 1);
              if (!((bitmap[j >> 6] >> (j & 63)) & 1ull)) {
                const u64 key = ((u64)bb << 16) | (u64)(65535 - j);
                if (key > best) best = key;
              }
            }
          }
        }
      }
      kall[t] = best;
      __syncthreads();
      for (int off = 256; off > 0; off >>= 1) {
        if (t < off && kall[t + off] > kall[t]) kall[t] = kall[t + off];
        __syncthreads();
      }
      const u64 wkey = kall[0];
      if (wkey == 0ull) break;
      if (t == 0) {
        const int j = 65535 - (int)(wkey & 0xFFFFull);
        bitmap[j >> 6] |= 1ull << (j & 63);
        const int cls = (j & 3) + 1;
        const int n = b * P_ + (j >> 2);
        const float4 rel = reinterpret_cast<const float4*>(boxreg)[n * 5 + cls];
        const float4 pr  = reinterpret_cast<const float4*>(props)[n];
        const float w  = pr.z - pr.x;
        const float h  = pr.w - pr.y;
        const float cx = pr.x + 0.5f * w;
        const float cy = pr.y + 0.5f * h;
        const float dxv = rel.x / 10.0f;
        const float dyv = rel.y / 10.0f;
        const float dwv = fminf(rel.z / 5.0f, CLIPV);
        const float dhv = fminf(rel.w / 5.0f, CLIPV);
        const float pcx = dxv * w + cx;
        const float pcy = dyv * h + cy;
        const float pw = expf(dwv) * w;
        const float ph = expf(dhv) * h;
        float x1 = pcx - 0.5f * pw, y1 = pcy - 0.5f * ph;
        float x2 = pcx + 0.5f * pw, y2 = pcy + 0.5f * ph;
        x1 = fminf(fmaxf(x1, 0.f), Wf);
        x2 = fminf(fmaxf(x2, 0.f), Wf);
        y1 = fminf(fmaxf(y1, 0.f), Hf);
        y2 = fminf(fmaxf(y2, 0.f), Hf);
        const float offv = (float)cls * maxv1;
        const float ox1 = x1 + offv, oy1 = y1 + offv;
        const float ox2 = x2 + offv, oy2 = y2 + offv;
        const float ar = (ox2 - ox1) * (oy2 - oy1);
        bool sup = false;
        for (int k2 = 0; k2 < kcount_s; ++k2) {
          const int ki = kidx[k2];
          const float ltx = fmaxf(cox1[ki], ox1);
          const float lty = fmaxf(coy1[ki], oy1);
          const float rbx = fminf(cox2[ki], ox2);
          const float rby = fminf(coy2[ki], oy2);
          const float iw = fmaxf(rbx - ltx, 0.f);
          const float ih = fmaxf(rby - lty, 0.f);
          const float inter = iw * ih;
          const float iou = inter / (carea[ki] + ar - inter);
          if (iou > 0.5f) { sup = true; break; }
        }
        if (!sup) {
          const int slot = CAP + nslow_s;
          cox1[slot] = ox1; coy1[slot] = oy1; cox2[slot] = ox2; coy2[slot] = oy2;
          carea[slot] = ar;
          cbx[slot] = make_float4(x1, y1, x2, y2);
          cscf[slot] = __uint_as_float((u32)(wkey >> 16));
          cj[slot] = j;
          kidx[kcount_s] = slot;
          ++nslow_s;
          ++kcount_s;
        }
      }
      __syncthreads();
      if (kcount_s >= K_) break;
    }
    __syncthreads();
  }
  __syncthreads();

  // ---- gather outputs ----
  const int kc = kcount_s;
  if (t < K_) {
    const int r = t;
    float ob0 = 0.f, ob1 = 0.f, ob2 = 0.f, ob3 = 0.f;
    float osc = 0.f, olab = 0.f, oside = 0.f;
    float od0 = 0.f, od1 = 0.f, od2 = 0.f;
    float ocon = 0.f, okeep = 0.f;
    if (r < kc) {
      const int idx = kidx[r];
      const int j = cj[idx];
      const int cls = (j & 3) + 1;
      const int n = b * P_ + (j >> 2);
      const float4 bx = cbx[idx];
      ob0 = bx.x; ob1 = bx.y; ob2 = bx.z; ob3 = bx.w;
      osc = cscf[idx];
      olab = (float)cls;
      oside = (handside[n * 5 + cls] > 0.f) ? 1.f : 0.f;
      od0 = dxdymag[n * 15 + cls * 3 + 0];
      od1 = dxdymag[n * 15 + cls * 3 + 1];
      od2 = dxdymag[n * 15 + cls * 3 + 2];
      float bvv = contact[n * 25 + cls * 5 + 0];
      int best = 0;
#pragma unroll
      for (int i = 1; i < 5; ++i) {
        const float ci = contact[n * 25 + cls * 5 + i];
        if (ci > bvv) { bvv = ci; best = i; }
      }
      ocon = (float)best;
      okeep = 1.f;
    }
    const int gb = b * K_ + r;
    out[gb * 4 + 0] = ob0;
    out[gb * 4 + 1] = ob1;
    out[gb * 4 + 2] = ob2;
    out[gb * 4 + 3] = ob3;
    out[3200 + gb] = osc;
    out[4000 + gb] = olab;
    out[4800 + gb] = oside;
    out[5600 + gb * 3 + 0] = od0;
    out[5600 + gb * 3 + 1] = od1;
    out[5600 + gb * 3 + 2] = od2;
    out[8000 + gb] = ocon;
    out[8800 + gb] = okeep;
  }
}

// ---------------------------------------------------------------------------
extern "C" void kernel_launch(void* const* d_in, const int* in_sizes, int n_in,
                              void* d_out, int out_size, void* d_ws, size_t ws_size,
                              hipStream_t stream) {
  const float* class_logits = (const float*)d_in[0];
  const float* box_reg      = (const float*)d_in[1];
  const float* handside     = (const float*)d_in[2];
  const float* dxdymag      = (const float*)d_in[3];
  const float* contact      = (const float*)d_in[4];
  const float* proposals    = (const float*)d_in[5];
  const int*   image_hw     = (const int*)d_in[6];
  float* out = (float*)d_out;

  char* ws = (char*)d_ws;
  u32* hist   = (u32*)ws;                          // 8*9216*4 = 294912 B
  int* wmax   = (int*)(ws + 294912);               // 32 B
  int* selcnt = (int*)(ws + 294944);               // 32 B
  u32* Xthr   = (u32*)(ws + 294976);               // 32 B
  int* remv   = (int*)(ws + 295008);               // 32 B
  u64* keybuf = (u64*)(ws + 295040);               // 8*512*8 = 32768 B

  hipMemsetAsync(d_ws, 0, 295040, stream);         // hist + counters
  prep_kernel<<<dim3(512), dim3(256), 0, stream>>>(
      class_logits, box_reg, proposals, image_hw, hist, wmax);
  thresh_kernel<<<dim3(B_), dim3(512), 0, stream>>>(hist, Xthr, remv);
  compact_kernel<<<dim3(512), dim3(256), 0, stream>>>(
      class_logits, Xthr, selcnt, keybuf);
  nms_kernel<<<dim3(B_), dim3(512), 0, stream>>>(
      class_logits, box_reg, proposals, image_hw, wmax, Xthr, remv, selcnt,
      keybuf, handside, dxdymag, contact, out);
}

// Round 5
// 84.756 us; speedup vs baseline: 11.6095x; 1.2541x over previous
//
#include <hip/hip_runtime.h>
#include <cstdint>

typedef unsigned int u32;
typedef unsigned long long u64;

constexpr int B_ = 8;
constexpr int P_ = 16384;
constexpr int K_ = 100;
constexpr int TSEL = 256;           // selection target
constexpr int CAP = 512;            // selection capacity
constexpr int SUB = 256;            // resolve sub-chunk (bitmask width)
constexpr int NBPAD = 9216;         // histogram bins, (bits>>12)-BASE12
constexpr u32 BASE12 = 0x3D4CCu;    // (bits(0.05f)+1)>>12
constexpr float SCORE_T = 0.05f;
constexpr float CLIPV = 4.135166556742356f;  // log(1000/16)

// softmax over 5 logits; s[c-1] = e[c]/ssum for c=1..4 (reference op order)
__device__ inline void softmax5(const float* __restrict__ logits, int n, float s[4]) {
  float l[5];
#pragma unroll
  for (int i = 0; i < 5; ++i) l[i] = logits[n * 5 + i];
  float mx = l[0];
#pragma unroll
  for (int i = 1; i < 5; ++i) mx = fmaxf(mx, l[i]);
  float e[5]; float ssum = 0.f;
#pragma unroll
  for (int i = 0; i < 5; ++i) { e[i] = expf(l[i] - mx); ssum += e[i]; }
#pragma unroll
  for (int c = 1; c < 5; ++c) s[c - 1] = e[c] / ssum;
}

// decode + clip, reference op order
__device__ inline float4 decode_clip(float4 rel, float w, float h, float cx,
                                     float cy, float Wf, float Hf) {
  const float dx = rel.x / 10.0f;
  const float dy = rel.y / 10.0f;
  const float dw = fminf(rel.z / 5.0f, CLIPV);
  const float dh = fminf(rel.w / 5.0f, CLIPV);
  const float pcx = dx * w + cx;
  const float pcy = dy * h + cy;
  const float pw = expf(dw) * w;
  const float ph = expf(dh) * h;
  float x1 = pcx - 0.5f * pw, y1 = pcy - 0.5f * ph;
  float x2 = pcx + 0.5f * pw, y2 = pcy + 0.5f * ph;
  x1 = fminf(fmaxf(x1, 0.f), Wf);
  x2 = fminf(fmaxf(x2, 0.f), Wf);
  y1 = fminf(fmaxf(y1, 0.f), Hf);
  y2 = fminf(fmaxf(y2, 0.f), Hf);
  return make_float4(x1, y1, x2, y2);
}

// ---------------------------------------------------------------------------
// Kernel 1 (wide): softmax + decode (per-image max coord) + global histogram
// of score bits (>>12).
// ---------------------------------------------------------------------------
__global__ __launch_bounds__(256) void prep_kernel(
    const float* __restrict__ logits, const float* __restrict__ boxreg,
    const float* __restrict__ props, const int* __restrict__ image_hw,
    u32* __restrict__ hist, int* __restrict__ wmax) {
  const int n = blockIdx.x * 256 + threadIdx.x;   // 512*256 == B*P
  const int b = n >> 14;

  float s[4];
  softmax5(logits, n, s);

  const float4 pr = reinterpret_cast<const float4*>(props)[n];
  const float w  = pr.z - pr.x;
  const float h  = pr.w - pr.y;
  const float cx = pr.x + 0.5f * w;
  const float cy = pr.y + 0.5f * h;
  const float Hf = (float)image_hw[0];
  const float Wf = (float)image_hw[1];

  float bmax = 0.f;
#pragma unroll
  for (int c = 1; c < 5; ++c) {
    const float4 rel = reinterpret_cast<const float4*>(boxreg)[n * 5 + c];
    const float4 bx = decode_clip(rel, w, h, cx, cy, Wf, Hf);
    bmax = fmaxf(bmax, fmaxf(fmaxf(bx.x, bx.z), fmaxf(bx.y, bx.w)));
    const float sv = s[c - 1];
    if (sv > SCORE_T) {
      const u32 bb = __float_as_uint(sv);
      u32 bin = (bb >> 12) - BASE12;
      if (bin > (u32)(NBPAD - 1)) bin = NBPAD - 1;
      atomicAdd(&hist[b * NBPAD + bin], 1u);
    }
  }

  __shared__ float red[256];
  red[threadIdx.x] = bmax;
  __syncthreads();
#pragma unroll
  for (int off = 128; off > 0; off >>= 1) {
    if (threadIdx.x < off) red[threadIdx.x] = fmaxf(red[threadIdx.x], red[threadIdx.x + off]);
    __syncthreads();
  }
  if (threadIdx.x == 0) atomicMax(&wmax[b], __float_as_int(red[0]));
}

// ---------------------------------------------------------------------------
// Kernel 2: per-image fused thresh + compact + sort + parallel-greedy NMS +
// gather. One 1024-thread block per image.
// ---------------------------------------------------------------------------
__global__ __launch_bounds__(1024) void nms_kernel(
    const float* __restrict__ logits, const float* __restrict__ boxreg,
    const float* __restrict__ props, const int* __restrict__ image_hw,
    const int* __restrict__ wmax, const u32* __restrict__ hist,
    const float* __restrict__ handside, const float* __restrict__ dxdymag,
    const float* __restrict__ contact, float* __restrict__ out) {
  const int b = blockIdx.x, t = threadIdx.x;
  const float maxv1 = __int_as_float(wmax[b]) + 1.0f;
  const float Hf = (float)image_hw[0];
  const float Wf = (float)image_hw[1];

  __shared__ int   part[512];
  __shared__ u32   X_s;
  __shared__ int   rem_s;
  __shared__ int   cnt_s;
  __shared__ u64   kall[CAP];
  __shared__ u64   skey[CAP];
  __shared__ float cox1[CAP + K_], coy1[CAP + K_], cox2[CAP + K_], coy2[CAP + K_];
  __shared__ float carea[CAP + K_], cscf[CAP + K_];
  __shared__ float4 cbx[CAP + K_];
  __shared__ int   cj[CAP + K_];
  __shared__ u64   supmask[SUB * 4];
  __shared__ u64   km[4];
  __shared__ int   chg;
  __shared__ int   kidx[K_];
  __shared__ int   kcount_s, nslow_s;
  __shared__ u64   red2[1024];
  __shared__ u64   bitmap[1024];

  if (t == 0) { kcount_s = 0; nslow_s = 0; }

  // ---- thresh: suffix-count scan of this image's histogram ----
  u32 hb[18]; int mysum = 0;
  if (t < 512) {
    const u32* h = hist + b * NBPAD;
    const int hi = NBPAD - t * 18, lo = hi - 18;   // t=0 owns TOP bins
#pragma unroll
    for (int q = 0; q < 18; ++q) { hb[q] = h[lo + q]; mysum += (int)hb[q]; }
    part[t] = mysum;
  }
  __syncthreads();
  for (int off = 1; off < 512; off <<= 1) {
    int v = 0;
    if (t < 512 && t >= off) v = part[t - off];
    __syncthreads();
    if (t < 512) part[t] += v;
    __syncthreads();
  }
  if (t < 512) {
    const int inc = part[t];
    const int pre = inc - mysum;
    const int tot = part[511];
    if (tot < TSEL) {
      if (t == 0) { X_s = BASE12 << 12; rem_s = 0; }
    } else if (pre < TSEL && inc >= TSEL) {        // unique boundary thread
      const int lo = NBPAD - t * 18 - 18;
      int cum = pre, k = lo;
      for (int q = 17; q >= 0; --q) {
        cum += (int)hb[q];
        if (cum >= TSEL) { k = lo + q; break; }
      }
      int C = cum;
      u32 Xbin;
      if (C > CAP) { C -= (int)hb[k - lo]; Xbin = (u32)(k + 1); }
      else Xbin = (u32)k;
      X_s = (BASE12 + Xbin) << 12;
      rem_s = tot - C;
    }
  }
  if (t < 512) kall[t] = 0ull;
  if (t == 0) cnt_s = 0;
  __syncthreads();
  const u32 X = X_s;

  // ---- compact: recompute softmax, collect keys >= X into LDS ----
  for (int p = t; p < P_; p += 1024) {
    const int n = b * P_ + p;
    float s[4];
    softmax5(logits, n, s);
#pragma unroll
    for (int c = 1; c < 5; ++c) {
      const float sv = s[c - 1];
      if (sv > SCORE_T) {
        const u32 bb = __float_as_uint(sv);
        if (bb >= X) {
          const int j = p * 4 + (c - 1);
          const int pos = atomicAdd(&cnt_s, 1);
          if (pos < CAP) kall[pos] = ((u64)bb << 16) | (u64)(65535 - j);
        }
      }
    }
  }
  __syncthreads();
  int C = cnt_s; if (C > CAP) C = CAP;

  // ---- rank-by-counting sort (keys unique; descending) ----
  if (t < 512) {
    const u64 my = kall[t];
    u32 r = 0;
    for (int u = 0; u < CAP; ++u) r += (kall[u] > my) ? 1u : 0u;
    if (t < C) skey[r] = my;
  }
  __syncthreads();

  // ---- decode candidates ----
  if (t < C) {
    const u64 key = skey[t];
    const int j = 65535 - (int)(key & 0xFFFFull);
    const int cls = (j & 3) + 1;
    const int n = b * P_ + (j >> 2);
    const float4 rel = reinterpret_cast<const float4*>(boxreg)[n * 5 + cls];
    const float4 pr  = reinterpret_cast<const float4*>(props)[n];
    const float w  = pr.z - pr.x;
    const float h  = pr.w - pr.y;
    const float cx = pr.x + 0.5f * w;
    const float cy = pr.y + 0.5f * h;
    const float4 bx = decode_clip(rel, w, h, cx, cy, Wf, Hf);
    const float offv = (float)cls * maxv1;
    const float ox1 = bx.x + offv, oy1 = bx.y + offv;
    const float ox2 = bx.z + offv, oy2 = bx.w + offv;
    cox1[t] = ox1; coy1[t] = oy1; cox2[t] = ox2; coy2[t] = oy2;
    carea[t] = (ox2 - ox1) * (oy2 - oy1);
    cbx[t] = bx;
    cscf[t] = __uint_as_float((u32)(key >> 16));
    cj[t] = j;
  }
  __syncthreads();

  // ---- resolve sub-chunks: pairwise masks + parallel greedy fixpoint ----
  const int wi = t >> 6, bi = t & 63;
  const u64 lowmask = bi ? (~0ull >> (64 - bi)) : 0ull;

  for (int s0 = 0; s0 < C; s0 += SUB) {
    const int S = min(SUB, C - s0);

    // alive = not suppressed by keeps from earlier chunks
    bool alive = false;
    if (t < S) {
      const float ax1 = cox1[s0 + t], ay1 = coy1[s0 + t];
      const float ax2 = cox2[s0 + t], ay2 = coy2[s0 + t];
      const float ar = carea[s0 + t];
      bool kd = false;
      const int kc0 = kcount_s;
      for (int k2 = 0; k2 < kc0; ++k2) {
        const int ki = kidx[k2];
        const float ltx = fmaxf(cox1[ki], ax1);
        const float lty = fmaxf(coy1[ki], ay1);
        const float rbx = fminf(cox2[ki], ax2);
        const float rby = fminf(coy2[ki], ay2);
        const float iw = fmaxf(rbx - ltx, 0.f);
        const float ih = fmaxf(rby - lty, 0.f);
        const float inter = iw * ih;
        const float iou = inter / (carea[ki] + ar - inter);
        if (iou > 0.5f) { kd = true; break; }
      }
      alive = !kd;
    }

    // pairwise suppression rows (self excluded)
    for (int task = t; task < S * 4; task += 1024) {
      const int i = task >> 2, wq = task & 3;
      const float ix1 = cox1[s0 + i], iy1 = coy1[s0 + i];
      const float ix2 = cox2[s0 + i], iy2 = coy2[s0 + i];
      const float ia = carea[s0 + i];
      u64 m = 0;
      const int qb = wq * 64, qe = min(qb + 64, S);
      for (int q = qb; q < qe; ++q) {
        if (q == i) continue;
        const float ltx = fmaxf(ix1, cox1[s0 + q]);
        const float lty = fmaxf(iy1, coy1[s0 + q]);
        const float rbx = fminf(ix2, cox2[s0 + q]);
        const float rby = fminf(iy2, coy2[s0 + q]);
        const float iw = fmaxf(rbx - ltx, 0.f);
        const float ih = fmaxf(rby - lty, 0.f);
        const float inter = iw * ih;
        const float iou = inter / (ia + carea[s0 + q] - inter);
        if (iou > 0.5f) m |= 1ull << (q - qb);
      }
      supmask[i * 4 + wq] = m;
    }
    __syncthreads();

    // row & below (suppressors j < i only), in registers
    u64 rb0 = 0, rb1 = 0, rb2 = 0, rb3 = 0;
    if (t < 256) {
      rb0 = supmask[t * 4 + 0];
      rb1 = supmask[t * 4 + 1];
      rb2 = supmask[t * 4 + 2];
      rb3 = supmask[t * 4 + 3];
      const u64 b0 = (wi > 0) ? ~0ull : lowmask;
      const u64 b1 = (wi > 1) ? ~0ull : ((wi == 1) ? lowmask : 0ull);
      const u64 b2 = (wi > 2) ? ~0ull : ((wi == 2) ? lowmask : 0ull);
      const u64 b3 = (wi == 3) ? lowmask : 0ull;
      rb0 &= b0; rb1 &= b1; rb2 &= b2; rb3 &= b3;
      const u64 bal = __ballot(alive ? 1 : 0);
      if (bi == 0) km[wi] = bal;
    }
    __syncthreads();

    // fixpoint iteration: k_i = alive_i && no kept j<i suppresses i
    while (true) {
      if (t == 0) chg = 0;
      __syncthreads();
      u64 nb = 0;
      if (t < 256) {
        const u64 k0 = km[0], k1 = km[1], k2 = km[2], k3 = km[3];
        const bool sup = ((rb0 & k0) | (rb1 & k1) | (rb2 & k2) | (rb3 & k3)) != 0ull;
        const bool kn = alive && !sup;
        nb = __ballot(kn ? 1 : 0);
        if (bi == 0 && nb != km[wi]) chg = 1;
      }
      __syncthreads();
      if (t < 256 && bi == 0) km[wi] = nb;
      __syncthreads();
      if (!chg) break;
    }

    // extract keeps in index order (== greedy order)
    const int kc0 = kcount_s;
    __syncthreads();
    if (t < 256) {
      const u64 kw = km[wi];
      if ((kw >> bi) & 1ull) {
        int pb = 0;
        if (wi > 0) pb += __popcll(km[0]);
        if (wi > 1) pb += __popcll(km[1]);
        if (wi > 2) pb += __popcll(km[2]);
        pb += __popcll(kw & lowmask);
        const int rank = kc0 + pb;
        if (rank < K_) kidx[rank] = s0 + t;
      }
      if (t == 0) {
        const int tot4 = __popcll(km[0]) + __popcll(km[1]) +
                         __popcll(km[2]) + __popcll(km[3]);
        kcount_s = min(kc0 + tot4, K_);
      }
    }
    __syncthreads();
    if (kcount_s >= K_) break;
  }

  // ---- slow-path continuation (exactness; not taken on benign data) ----
  if (kcount_s < K_ && rem_s > 0) {
    bitmap[t] = 0ull;
    __syncthreads();
    while (true) {
      u64 best = 0ull;
      for (int p = t; p < P_; p += 1024) {
        const int n = b * P_ + p;
        float s[4];
        softmax5(logits, n, s);
#pragma unroll
        for (int c = 1; c < 5; ++c) {
          const float sv = s[c - 1];
          if (sv > SCORE_T) {
            const u32 bb = __float_as_uint(sv);
            if (bb < X) {
              const int j = p * 4 + (c - 1);
              if (!((bitmap[j >> 6] >> (j & 63)) & 1ull)) {
                const u64 key = ((u64)bb << 16) | (u64)(65535 - j);
                if (key > best) best = key;
              }
            }
          }
        }
      }
      red2[t] = best;
      __syncthreads();
      for (int off = 512; off > 0; off >>= 1) {
        if (t < off && red2[t + off] > red2[t]) red2[t] = red2[t + off];
        __syncthreads();
      }
      const u64 wkey = red2[0];
      if (wkey == 0ull) break;
      if (t == 0) {
        const int j = 65535 - (int)(wkey & 0xFFFFull);
        bitmap[j >> 6] |= 1ull << (j & 63);
        const int cls = (j & 3) + 1;
        const int n = b * P_ + (j >> 2);
        const float4 rel = reinterpret_cast<const float4*>(boxreg)[n * 5 + cls];
        const float4 pr  = reinterpret_cast<const float4*>(props)[n];
        const float w  = pr.z - pr.x;
        const float h  = pr.w - pr.y;
        const float cx = pr.x + 0.5f * w;
        const float cy = pr.y + 0.5f * h;
        const float4 bx = decode_clip(rel, w, h, cx, cy, Wf, Hf);
        const float offv = (float)cls * maxv1;
        const float ox1 = bx.x + offv, oy1 = bx.y + offv;
        const float ox2 = bx.z + offv, oy2 = bx.w + offv;
        const float ar = (ox2 - ox1) * (oy2 - oy1);
        bool sup = false;
        for (int k2 = 0; k2 < kcount_s; ++k2) {
          const int ki = kidx[k2];
          const float ltx = fmaxf(cox1[ki], ox1);
          const float lty = fmaxf(coy1[ki], oy1);
          const float rbx = fminf(cox2[ki], ox2);
          const float rby = fminf(coy2[ki], oy2);
          const float iw = fmaxf(rbx - ltx, 0.f);
          const float ih = fmaxf(rby - lty, 0.f);
          const float inter = iw * ih;
          const float iou = inter / (carea[ki] + ar - inter);
          if (iou > 0.5f) { sup = true; break; }
        }
        if (!sup) {
          const int slot = CAP + nslow_s;
          cox1[slot] = ox1; coy1[slot] = oy1; cox2[slot] = ox2; coy2[slot] = oy2;
          carea[slot] = ar;
          cbx[slot] = bx;
          cscf[slot] = __uint_as_float((u32)(wkey >> 16));
          cj[slot] = j;
          kidx[kcount_s] = slot;
          ++nslow_s;
          ++kcount_s;
        }
      }
      __syncthreads();
      if (kcount_s >= K_) break;
    }
    __syncthreads();
  }
  __syncthreads();

  // ---- gather outputs ----
  const int kc = kcount_s;
  if (t < K_) {
    const int r = t;
    float ob0 = 0.f, ob1 = 0.f, ob2 = 0.f, ob3 = 0.f;
    float osc = 0.f, olab = 0.f, oside = 0.f;
    float od0 = 0.f, od1 = 0.f, od2 = 0.f;
    float ocon = 0.f, okeep = 0.f;
    if (r < kc) {
      const int idx = kidx[r];
      const int j = cj[idx];
      const int cls = (j & 3) + 1;
      const int n = b * P_ + (j >> 2);
      const float4 bx = cbx[idx];
      ob0 = bx.x; ob1 = bx.y; ob2 = bx.z; ob3 = bx.w;
      osc = cscf[idx];
      olab = (float)cls;
      oside = (handside[n * 5 + cls] > 0.f) ? 1.f : 0.f;   // sigmoid>0.5 <=> x>0
      od0 = dxdymag[n * 15 + cls * 3 + 0];
      od1 = dxdymag[n * 15 + cls * 3 + 1];
      od2 = dxdymag[n * 15 + cls * 3 + 2];
      float bvv = contact[n * 25 + cls * 5 + 0];
      int best = 0;
#pragma unroll
      for (int i = 1; i < 5; ++i) {
        const float ci = contact[n * 25 + cls * 5 + i];
        if (ci > bvv) { bvv = ci; best = i; }
      }
      ocon = (float)best;
      okeep = 1.f;
    }
    const int gb = b * K_ + r;
    out[gb * 4 + 0] = ob0;
    out[gb * 4 + 1] = ob1;
    out[gb * 4 + 2] = ob2;
    out[gb * 4 + 3] = ob3;
    out[3200 + gb] = osc;
    out[4000 + gb] = olab;
    out[4800 + gb] = oside;
    out[5600 + gb * 3 + 0] = od0;
    out[5600 + gb * 3 + 1] = od1;
    out[5600 + gb * 3 + 2] = od2;
    out[8000 + gb] = ocon;
    out[8800 + gb] = okeep;
  }
}

// ---------------------------------------------------------------------------
extern "C" void kernel_launch(void* const* d_in, const int* in_sizes, int n_in,
                              void* d_out, int out_size, void* d_ws, size_t ws_size,
                              hipStream_t stream) {
  const float* class_logits = (const float*)d_in[0];
  const float* box_reg      = (const float*)d_in[1];
  const float* handside     = (const float*)d_in[2];
  const float* dxdymag      = (const float*)d_in[3];
  const float* contact      = (const float*)d_in[4];
  const float* proposals    = (const float*)d_in[5];
  const int*   image_hw     = (const int*)d_in[6];
  float* out = (float*)d_out;

  char* ws = (char*)d_ws;
  u32* hist = (u32*)ws;                    // 8*9216*4 = 294912 B
  int* wmax = (int*)(ws + 294912);         // 32 B

  hipMemsetAsync(d_ws, 0, 294944, stream); // hist + wmax
  prep_kernel<<<dim3(512), dim3(256), 0, stream>>>(
      class_logits, box_reg, proposals, image_hw, hist, wmax);
  nms_kernel<<<dim3(B_), dim3(1024), 0, stream>>>(
      class_logits, box_reg, proposals, image_hw, wmax, hist,
      handside, dxdymag, contact, out);
}

// Round 6
// 51.822 us; speedup vs baseline: 18.9876x; 1.6355x over previous
//
#include <hip/hip_runtime.h>
#include <cstdint>

typedef unsigned int u32;
typedef unsigned long long u64;

constexpr int B_ = 8;
constexpr int P_ = 16384;
constexpr int K_ = 100;
constexpr int M_ = P_ * 4;            // 65536 candidates per image, j = p*4+(cls-1)
constexpr int TSEL = 192;             // selection target
constexpr int CAP = 256;              // selection capacity (= one resolve chunk)
constexpr u32 BASE13 = 0x3D4CCCCEu >> 13;   // first bin: score bits strictly > 0.05f
constexpr int NBP = 4608;             // padded bin count (576 threads * 8 bins)
constexpr float SCORE_T = 0.05f;
constexpr float CLIPV = 4.135166556742356f;  // log(1000/16)

// swizzled candidate slot: rotate low-6 bits by 4*(group) -> the 4 simultaneous
// row-group reads in the pairwise phase hit 2 banks (2-way == free) not 4-way.
__device__ inline int aphys(int i) {
  return (i < CAP) ? ((((i & 63) + ((i >> 6) << 2)) & 63) | (i & 192)) : i;
}

// ---------------------------------------------------------------------------
// Kernel 1 (wide, 512 blocks): softmax + decode + clip; store scores [B*M],
// boxes [B*M,4], per-block max coordinate (no atomics, no memset needed).
// ---------------------------------------------------------------------------
__global__ __launch_bounds__(256) void prep_kernel(
    const float* __restrict__ logits,     // [N,5]
    const float* __restrict__ boxreg,     // [N,20]
    const float* __restrict__ props,      // [N,4]
    const int*  __restrict__ image_hw,    // {H,W}
    float* __restrict__ wboxes,           // [B*M,4]
    float* __restrict__ wscores,          // [B*M]
    float* __restrict__ wblockmax)        // [512]
{
  const int n = blockIdx.x * 256 + threadIdx.x;   // 512*256 == B*P

  float l[5];
#pragma unroll
  for (int i = 0; i < 5; ++i) l[i] = logits[n * 5 + i];
  float mx = l[0];
#pragma unroll
  for (int i = 1; i < 5; ++i) mx = fmaxf(mx, l[i]);
  float e[5]; float ssum = 0.f;
#pragma unroll
  for (int i = 0; i < 5; ++i) { e[i] = expf(l[i] - mx); ssum += e[i]; }

  const float4 pr = reinterpret_cast<const float4*>(props)[n];
  const float w  = pr.z - pr.x;
  const float h  = pr.w - pr.y;
  const float cx = pr.x + 0.5f * w;
  const float cy = pr.y + 0.5f * h;
  const float Hf = (float)image_hw[0];
  const float Wf = (float)image_hw[1];

  float bmax = 0.f;
  float sc[4];
#pragma unroll
  for (int c = 1; c < 5; ++c) {
    const float4 rel = reinterpret_cast<const float4*>(boxreg)[n * 5 + c];
    const float dx = rel.x / 10.0f;
    const float dy = rel.y / 10.0f;
    const float dw = fminf(rel.z / 5.0f, CLIPV);
    const float dh = fminf(rel.w / 5.0f, CLIPV);
    const float pcx = dx * w + cx;
    const float pcy = dy * h + cy;
    const float pw = expf(dw) * w;
    const float ph = expf(dh) * h;
    float x1 = pcx - 0.5f * pw, y1 = pcy - 0.5f * ph;
    float x2 = pcx + 0.5f * pw, y2 = pcy + 0.5f * ph;
    x1 = fminf(fmaxf(x1, 0.f), Wf);
    x2 = fminf(fmaxf(x2, 0.f), Wf);
    y1 = fminf(fmaxf(y1, 0.f), Hf);
    y2 = fminf(fmaxf(y2, 0.f), Hf);
    reinterpret_cast<float4*>(wboxes)[n * 4 + (c - 1)] = make_float4(x1, y1, x2, y2);
    bmax = fmaxf(bmax, fmaxf(fmaxf(x1, x2), fmaxf(y1, y2)));
    sc[c - 1] = e[c] / ssum;
  }
  reinterpret_cast<float4*>(wscores)[n] = make_float4(sc[0], sc[1], sc[2], sc[3]);

  __shared__ float red[256];
  red[threadIdx.x] = bmax;
  __syncthreads();
#pragma unroll
  for (int off = 128; off > 0; off >>= 1) {
    if (threadIdx.x < off) red[threadIdx.x] = fmaxf(red[threadIdx.x], red[threadIdx.x + off]);
    __syncthreads();
  }
  if (threadIdx.x == 0) wblockmax[blockIdx.x] = red[0];
}

// ---------------------------------------------------------------------------
// Kernel 2 (8 blocks x 1024): LDS hist -> exact threshold -> compact -> rank
// sort -> pairwise masks -> parallel greedy fixpoint -> gather.
// ---------------------------------------------------------------------------
__global__ __launch_bounds__(1024) void nms_kernel(
    const float* __restrict__ wboxes, const float* __restrict__ wscores,
    const float* __restrict__ wblockmax,
    const float* __restrict__ handside, const float* __restrict__ dxdymag,
    const float* __restrict__ contact, float* __restrict__ out)
{
  const int b = blockIdx.x, t = threadIdx.x;
  const float4* boxes4 = reinterpret_cast<const float4*>(wboxes);
  const float4* sc4 = reinterpret_cast<const float4*>(wscores) + (size_t)b * (M_ / 4);

  __shared__ u32   hist[NBP];
  __shared__ int   wavesum[16];
  __shared__ float maxv_s;
  __shared__ u32   X_s;
  __shared__ int   cnt_s;
  __shared__ u64   kall[CAP];
  __shared__ u64   skey[CAP];
  __shared__ float4 cb4[CAP + K_];     // offset coords, swizzled slots
  __shared__ float carea[CAP + K_];
  __shared__ float cscf[CAP + K_];
  __shared__ int   cj[CAP + K_];
  __shared__ u64   supmask[CAP * 4];   // logical index * 4
  __shared__ u64   km[4];
  __shared__ int   chg;
  __shared__ int   kidx[K_];
  __shared__ int   kcount_s, nslow_s;
  __shared__ u64   red2[1024];
  __shared__ u64   bitmap[1024];

  // per-image max coordinate from the 64 prep block maxima
  if (t < 64) {
    float v = wblockmax[b * 64 + t];
#pragma unroll
    for (int off = 32; off > 0; off >>= 1) v = fmaxf(v, __shfl_xor(v, off));
    if (t == 0) maxv_s = v;
  }
  if (t == 0) { kcount_s = 0; nslow_s = 0; cnt_s = 0; X_s = BASE13 << 13; }
  for (int i = t; i < NBP; i += 1024) hist[i] = 0;
  __syncthreads();
  const float maxv1 = maxv_s + 1.0f;   // (boxes.max() + 1.0)

  // ---- histogram of passing score bits (>>13) ----
  for (int i = t; i < M_ / 4; i += 1024) {
    const float4 v = sc4[i];
    const float ss[4] = {v.x, v.y, v.z, v.w};
#pragma unroll
    for (int c = 0; c < 4; ++c) {
      if (ss[c] > SCORE_T) {
        u32 bin = (__float_as_uint(ss[c]) >> 13) - BASE13;
        if (bin >= (u32)NBP) bin = NBP - 1;
        atomicAdd(&hist[bin], 1u);
      }
    }
  }
  __syncthreads();

  // ---- suffix counts (thread t owns 8 bins descending from the top) ----
  u32 hb[8]; int mysum = 0, inc = 0;
  const int lo = NBP - t * 8 - 8;
  if (t < 576) {
#pragma unroll
    for (int q = 0; q < 8; ++q) { hb[q] = hist[lo + q]; mysum += (int)hb[q]; }
    inc = mysum;
#pragma unroll
    for (int off = 1; off < 64; off <<= 1) {
      const int vv = __shfl_up(inc, off);
      if ((t & 63) >= off) inc += vv;
    }
    if ((t & 63) == 63) wavesum[t >> 6] = inc;
  }
  __syncthreads();
  if (t < 576) {
    int above = 0;
    for (int w = 0; w < (t >> 6); ++w) above += wavesum[w];
    inc += above;
    const int pre = inc - mysum;
    if (pre < TSEL && inc >= TSEL) {           // unique boundary thread
      int cum = pre, kb = lo, qs = 7;
      for (int q = 7; q >= 0; --q) {           // top bin of chunk first
        cum += (int)hb[q];
        if (cum >= TSEL) { kb = lo + q; qs = q; break; }
      }
      u32 Xbin = (cum > CAP) ? (u32)(kb + 1)   // tie-heavy bin: exclude (exact)
                             : (u32)kb;
      X_s = (BASE13 + Xbin) << 13;
    }
  }
  if (t < CAP) kall[t] = 0ull;
  __syncthreads();
  const u32 X = X_s;

  // ---- compact: keys with score bits >= X (count == hist count <= CAP) ----
  for (int i = t; i < M_ / 4; i += 1024) {
    const float4 v = sc4[i];
    const float ss[4] = {v.x, v.y, v.z, v.w};
    const int j0 = i * 4;
#pragma unroll
    for (int c = 0; c < 4; ++c) {
      if (ss[c] > SCORE_T) {
        const u32 bb = __float_as_uint(ss[c]);
        if (bb >= X) {
          const int pos = atomicAdd(&cnt_s, 1);
          if (pos < CAP) kall[pos] = ((u64)bb << 16) | (u64)(65535 - (j0 + c));
        }
      }
    }
  }
  __syncthreads();
  const int C = min(cnt_s, CAP);

  // ---- rank-by-counting sort (unique keys, descending) ----
  if (t < CAP) {
    const u64 my = kall[t];
    u32 r = 0;
    for (int u = 0; u < CAP; ++u) r += (kall[u] > my) ? 1u : 0u;
    if (t < C) skey[r] = my;
  }
  __syncthreads();

  // ---- candidate setup from stored boxes ----
  if (t < C) {
    const u64 key = skey[t];
    const int j = 65535 - (int)(key & 0xFFFFull);
    const int cls = (j & 3) + 1;
    const float4 bx = boxes4[(size_t)b * M_ + j];
    const float offv = (float)cls * maxv1;
    const float ox1 = bx.x + offv, oy1 = bx.y + offv;
    const float ox2 = bx.z + offv, oy2 = bx.w + offv;
    const int ph = aphys(t);
    cb4[ph] = make_float4(ox1, oy1, ox2, oy2);
    carea[ph] = (ox2 - ox1) * (oy2 - oy1);
    cscf[ph] = __uint_as_float((u32)(key >> 16));
    cj[ph] = j;
  }
  __syncthreads();

  // ---- pairwise suppression rows (self excluded) ----
  for (int task = t; task < C * 4; task += 1024) {
    const int i = task >> 2, wq = task & 3;
    const float4 ib = cb4[aphys(i)];
    const float ia = carea[aphys(i)];
    u64 m = 0;
    const int qb = wq * 64, qe = min(qb + 64, C);
    for (int q = qb; q < qe; ++q) {
      if (q == i) continue;
      const int qp = aphys(q);
      const float4 qbx = cb4[qp];
      const float ltx = fmaxf(ib.x, qbx.x);
      const float lty = fmaxf(ib.y, qbx.y);
      const float rbx = fminf(ib.z, qbx.z);
      const float rby = fminf(ib.w, qbx.w);
      const float iw = fmaxf(rbx - ltx, 0.f);
      const float ih = fmaxf(rby - lty, 0.f);
      const float inter = iw * ih;
      const float iou = inter / (ia + carea[qp] - inter);  // a1+a2-inter
      if (iou > 0.5f) m |= 1ull << (q - qb);               // NaN -> false (ref)
    }
    supmask[i * 4 + wq] = m;
  }
  __syncthreads();

  // ---- parallel greedy fixpoint (unique fixpoint == greedy; <= C+1 rounds) ----
  const int wi = t >> 6, bi = t & 63;
  const u64 lowmask = bi ? (~0ull >> (64 - bi)) : 0ull;
  u64 rb0 = 0, rb1 = 0, rb2 = 0, rb3 = 0;
  const bool alive = (t < C);
  if (t < CAP) {
    rb0 = supmask[t * 4 + 0];
    rb1 = supmask[t * 4 + 1];
    rb2 = supmask[t * 4 + 2];
    rb3 = supmask[t * 4 + 3];
    const u64 m0 = (wi > 0) ? ~0ull : lowmask;
    const u64 m1 = (wi > 1) ? ~0ull : ((wi == 1) ? lowmask : 0ull);
    const u64 m2 = (wi > 2) ? ~0ull : ((wi == 2) ? lowmask : 0ull);
    const u64 m3 = (wi == 3) ? lowmask : 0ull;
    rb0 &= m0; rb1 &= m1; rb2 &= m2; rb3 &= m3;   // suppressors j < i only
    const u64 bal = __ballot(alive ? 1 : 0);
    if (bi == 0) km[wi] = bal;
  }
  __syncthreads();
  while (true) {
    if (t == 0) chg = 0;
    __syncthreads();
    u64 nb = 0;
    if (t < CAP) {
      const u64 k0 = km[0], k1 = km[1], k2 = km[2], k3 = km[3];
      const bool sup = ((rb0 & k0) | (rb1 & k1) | (rb2 & k2) | (rb3 & k3)) != 0ull;
      const bool kn = alive && !sup;
      nb = __ballot(kn ? 1 : 0);
      if (bi == 0 && nb != km[wi]) chg = 1;
    }
    __syncthreads();
    if (t < CAP && bi == 0) km[wi] = nb;
    __syncthreads();
    if (!chg) break;
  }

  // ---- extract keeps in index order (== greedy pop order) ----
  if (t < CAP) {
    const u64 kw = km[wi];
    if ((kw >> bi) & 1ull) {
      int pb = 0;
      if (wi > 0) pb += __popcll(km[0]);
      if (wi > 1) pb += __popcll(km[1]);
      if (wi > 2) pb += __popcll(km[2]);
      pb += __popcll(kw & lowmask);
      if (pb < K_) kidx[pb] = t;
    }
    if (t == 0) {
      kcount_s = min(__popcll(km[0]) + __popcll(km[1]) +
                     __popcll(km[2]) + __popcll(km[3]), K_);
    }
  }
  __syncthreads();

  // ---- slow-path continuation (exactness; empty/instant on benign data) ----
  if (kcount_s < K_) {
    bitmap[t] = 0ull;
    __syncthreads();
    while (true) {
      u64 best = 0ull;
      for (int i = t; i < M_ / 4; i += 1024) {
        const float4 v = sc4[i];
        const float ss[4] = {v.x, v.y, v.z, v.w};
#pragma unroll
        for (int c = 0; c < 4; ++c) {
          if (ss[c] > SCORE_T) {
            const u32 bb = __float_as_uint(ss[c]);
            if (bb < X) {
              const int j = i * 4 + c;
              if (!((bitmap[j >> 6] >> (j & 63)) & 1ull)) {
                const u64 key = ((u64)bb << 16) | (u64)(65535 - j);
                if (key > best) best = key;
              }
            }
          }
        }
      }
      red2[t] = best;
      __syncthreads();
      for (int off = 512; off > 0; off >>= 1) {
        if (t < off && red2[t + off] > red2[t]) red2[t] = red2[t + off];
        __syncthreads();
      }
      const u64 wkey = red2[0];
      if (wkey == 0ull) break;
      if (t == 0) {
        const int j = 65535 - (int)(wkey & 0xFFFFull);
        bitmap[j >> 6] |= 1ull << (j & 63);
        const int cls = (j & 3) + 1;
        const float4 bx = boxes4[(size_t)b * M_ + j];
        const float offv = (float)cls * maxv1;
        const float ox1 = bx.x + offv, oy1 = bx.y + offv;
        const float ox2 = bx.z + offv, oy2 = bx.w + offv;
        const float ar = (ox2 - ox1) * (oy2 - oy1);
        bool sup = false;
        for (int k2 = 0; k2 < kcount_s; ++k2) {
          const int ki = aphys(kidx[k2]);
          const float4 kb = cb4[ki];
          const float ltx = fmaxf(kb.x, ox1);
          const float lty = fmaxf(kb.y, oy1);
          const float rbx = fminf(kb.z, ox2);
          const float rby = fminf(kb.w, oy2);
          const float iw = fmaxf(rbx - ltx, 0.f);
          const float ih = fmaxf(rby - lty, 0.f);
          const float inter = iw * ih;
          const float iou = inter / (carea[ki] + ar - inter);
          if (iou > 0.5f) { sup = true; break; }
        }
        if (!sup) {
          const int slot = CAP + nslow_s;        // aphys(slot) == slot
          cb4[slot] = make_float4(ox1, oy1, ox2, oy2);
          carea[slot] = ar;
          cscf[slot] = __uint_as_float((u32)(wkey >> 16));
          cj[slot] = j;
          kidx[kcount_s] = slot;
          ++nslow_s;
          ++kcount_s;
        }
      }
      __syncthreads();
      if (kcount_s >= K_) break;
    }
    __syncthreads();
  }
  __syncthreads();

  // ---- gather outputs ----
  const int kc = kcount_s;
  if (t < K_) {
    const int r = t;
    float ob0 = 0.f, ob1 = 0.f, ob2 = 0.f, ob3 = 0.f;
    float osc = 0.f, olab = 0.f, oside = 0.f;
    float od0 = 0.f, od1 = 0.f, od2 = 0.f;
    float ocon = 0.f, okeep = 0.f;
    if (r < kc) {
      const int idx = kidx[r];
      const int ph = aphys(idx);
      const int j = cj[ph];
      const int cls = (j & 3) + 1;
      const int n = b * P_ + (j >> 2);
      const float4 bx = boxes4[(size_t)b * M_ + j];   // unshifted output box
      ob0 = bx.x; ob1 = bx.y; ob2 = bx.z; ob3 = bx.w;
      osc = cscf[ph];
      olab = (float)cls;
      oside = (handside[n * 5 + cls] > 0.f) ? 1.f : 0.f;  // sigmoid>0.5 <=> x>0
      od0 = dxdymag[n * 15 + cls * 3 + 0];
      od1 = dxdymag[n * 15 + cls * 3 + 1];
      od2 = dxdymag[n * 15 + cls * 3 + 2];
      float bvv = contact[n * 25 + cls * 5 + 0];
      int best = 0;
#pragma unroll
      for (int i = 1; i < 5; ++i) {
        const float ci = contact[n * 25 + cls * 5 + i];
        if (ci > bvv) { bvv = ci; best = i; }
      }
      ocon = (float)best;
      okeep = 1.f;
    }
    const int gb = b * K_ + r;
    out[gb * 4 + 0] = ob0;
    out[gb * 4 + 1] = ob1;
    out[gb * 4 + 2] = ob2;
    out[gb * 4 + 3] = ob3;
    out[3200 + gb] = osc;
    out[4000 + gb] = olab;
    out[4800 + gb] = oside;
    out[5600 + gb * 3 + 0] = od0;
    out[5600 + gb * 3 + 1] = od1;
    out[5600 + gb * 3 + 2] = od2;
    out[8000 + gb] = ocon;
    out[8800 + gb] = okeep;
  }
}

// ---------------------------------------------------------------------------
extern "C" void kernel_launch(void* const* d_in, const int* in_sizes, int n_in,
                              void* d_out, int out_size, void* d_ws, size_t ws_size,
                              hipStream_t stream) {
  const float* class_logits = (const float*)d_in[0];
  const float* box_reg      = (const float*)d_in[1];
  const float* handside     = (const float*)d_in[2];
  const float* dxdymag      = (const float*)d_in[3];
  const float* contact      = (const float*)d_in[4];
  const float* proposals    = (const float*)d_in[5];
  const int*   image_hw     = (const int*)d_in[6];
  float* out = (float*)d_out;

  char* ws = (char*)d_ws;
  float* wboxes    = (float*)ws;                               // 8 MiB
  float* wscores   = (float*)(ws + (size_t)8 * 1024 * 1024);   // 2 MiB
  float* wblockmax = (float*)(ws + (size_t)10 * 1024 * 1024);  // 2 KiB

  prep_kernel<<<dim3(512), dim3(256), 0, stream>>>(
      class_logits, box_reg, proposals, image_hw, wboxes, wscores, wblockmax);
  nms_kernel<<<dim3(B_), dim3(1024), 0, stream>>>(
      wboxes, wscores, wblockmax, handside, dxdymag, contact, out);
}